// Round 6
// baseline (494.948 us; speedup 1.0000x reference)
//
#include <hip/hip_runtime.h>
#include <math.h>

#define DMODEL 256
#define NHEAD 8
#define NLVL 3
#define NPTS 4
#define HDIM 32
#define QLEN 10000
#define BATCH 4
#define NQ (BATCH * QLEN)

__device__ __forceinline__ float tanh_fast(float x)
{
    const float ax = fabsf(x);
    const float e  = __expf(-2.f * ax);
    const float t  = (1.f - e) / (1.f + e);
    return copysignf(t, x);
}

__device__ __forceinline__ unsigned short f2bf(float f)
{
    unsigned int u = __float_as_uint(f);
    u = (u + 0x7FFFu + ((u >> 16) & 1u)) >> 16;
    return (unsigned short)u;
}

__device__ __forceinline__ float bf2f(unsigned short s)
{
    return __uint_as_float(((unsigned int)s) << 16);
}

// ---------------------------------------------------------------------------
// K1: value projection -> bf16, all 3 levels in one grid, software-pipelined.
// ---------------------------------------------------------------------------
__global__ __launch_bounds__(256) void vproj_kernel(
    const float* __restrict__ feat0, const float* __restrict__ feat1,
    const float* __restrict__ feat2, const float* __restrict__ Wv,
    const float* __restrict__ bv,
    unsigned short* __restrict__ v0, unsigned short* __restrict__ v1,
    unsigned short* __restrict__ v2)
{
    __shared__ float As[16 * 64];    // [kk][pos]
    __shared__ float Ws[16 * 256];   // [kk][col]

    const int bx = blockIdx.x;
    const int b  = blockIdx.y;

    const float* feat;
    unsigned short* vout;
    int HW, pos0;
    if (bx < 157)      { feat = feat0; vout = v0; HW = 10000; pos0 = bx * 64; }
    else if (bx < 197) { feat = feat1; vout = v1; HW = 2500;  pos0 = (bx - 157) * 64; }
    else               { feat = feat2; vout = v2; HW = 625;   pos0 = (bx - 197) * 64; }

    const int tid  = threadIdx.x;
    const int tp   = tid >> 5;
    const int tc   = tid & 31;

    // staging indices (per-thread constants)
    const int ap   = tid & 63;            // position within tile
    const int ak   = tid >> 6;            // base kk (stride 4)
    const int wkk  = tid >> 6;            // Ws: g = tid + 256j -> kk = g>>6 = wkk + 4j
    const int wc4  = (tid & 63) * 4;      // col within row

    float acc[8][8];
#pragma unroll
    for (int i = 0; i < 8; ++i)
#pragma unroll
        for (int j = 0; j < 8; ++j) acc[i][j] = 0.f;

    const float* fb = feat + (size_t)b * DMODEL * HW;
    const bool pvalid = (pos0 + ap) < HW;

    float  areg[4];
    float4 wreg[4];

    auto LOAD = [&](int k0) {
#pragma unroll
        for (int it = 0; it < 4; ++it) {
            const int kk = ak + it * 4;
            areg[it] = pvalid ? fb[(size_t)(k0 + kk) * HW + pos0 + ap] : 0.f;
        }
#pragma unroll
        for (int j = 0; j < 4; ++j)
            wreg[j] = *(const float4*)&Wv[(size_t)(k0 + wkk + 4 * j) * 256 + wc4];
    };
    auto STORE = [&]() {
#pragma unroll
        for (int it = 0; it < 4; ++it)
            As[(ak + it * 4) * 64 + ap] = areg[it];
#pragma unroll
        for (int j = 0; j < 4; ++j)
            *(float4*)&Ws[(wkk + 4 * j) * 256 + wc4] = wreg[j];
    };

    LOAD(0);
    for (int step = 0; step < 16; ++step) {
        STORE();
        __syncthreads();
        if (step < 15) LOAD((step + 1) * 16);

#pragma unroll
        for (int kk = 0; kk < 16; ++kk) {
            const float4 a0 = *(const float4*)&As[kk * 64 + tp * 8];
            const float4 a1 = *(const float4*)&As[kk * 64 + tp * 8 + 4];
            const float a[8] = {a0.x, a0.y, a0.z, a0.w, a1.x, a1.y, a1.z, a1.w};
            float w[8];
#pragma unroll
            for (int jj = 0; jj < 4; ++jj) {
                const float2 wv = *(const float2*)&Ws[kk * 256 + 2 * tc + 64 * jj];
                w[2 * jj]     = wv.x;
                w[2 * jj + 1] = wv.y;
            }
#pragma unroll
            for (int i = 0; i < 8; ++i)
#pragma unroll
                for (int j = 0; j < 8; ++j)
                    acc[i][j] = fmaf(a[i], w[j], acc[i][j]);
        }
        __syncthreads();
    }

    float bb[8];
#pragma unroll
    for (int jj = 0; jj < 4; ++jj) {
        const float2 bvv = *(const float2*)&bv[2 * tc + 64 * jj];
        bb[2 * jj]     = bvv.x;
        bb[2 * jj + 1] = bvv.y;
    }

    unsigned short* vb = vout + (size_t)b * HW * 256;
#pragma unroll
    for (int i = 0; i < 8; ++i) {
        const int p = pos0 + tp * 8 + i;
        if (p < HW) {
            unsigned int* vp = (unsigned int*)(vb + (size_t)p * 256);
#pragma unroll
            for (int jj = 0; jj < 4; ++jj) {
                const unsigned int lo = f2bf(acc[i][2 * jj]     + bb[2 * jj]);
                const unsigned int hi = f2bf(acc[i][2 * jj + 1] + bb[2 * jj + 1]);
                vp[tc + 32 * jj] = lo | (hi << 16);
            }
        }
    }
}

// ---------------------------------------------------------------------------
// K2: query-side GEMM + epilogue.  64 rows/block (625 blocks), 256 threads:
// thread = (r0 = tid>>3 in 0..31, h = tid&7), owns rows {r0, r0+32} with
// acc[2][36].  W in LINEAR LDS layout [kk][288] (conflict-free staging,
// 16B-aligned per-head float4 reads).  Software-pipelined staging.
// ---------------------------------------------------------------------------
__global__ __launch_bounds__(256) void qparam_kernel(
    const float* __restrict__ query, const float* __restrict__ ref,
    const float* __restrict__ Woff, const float* __restrict__ boff,
    const float* __restrict__ Wattn, const float* __restrict__ battn,
    float* __restrict__ params)
{
    __shared__ float Qs[16 * 68];    // [kk][r], stride 68
    __shared__ float WL[16 * 288];   // [kk][col] linear

    const int row0 = blockIdx.x * 64;
    const int tid  = threadIdx.x;
    const int h    = tid & 7;
    const int r0   = tid >> 3;       // 0..31

    // Q staging: float4 per thread
    const int sr = tid >> 2;          // 0..63
    const int sk = (tid & 3) * 4;     // 0,4,8,12

    // W staging: 5 float4 slots (1152 total), precomputed indices
    int wkk[5], wc4[5];
    bool wok[5];
#pragma unroll
    for (int j = 0; j < 5; ++j) {
        const int g = tid + j * 256;
        wok[j] = (g < 1152);
        wkk[j] = g / 72;
        wc4[j] = g - wkk[j] * 72;
    }

    float acc[2][36];
#pragma unroll
    for (int i = 0; i < 2; ++i)
#pragma unroll
        for (int j = 0; j < 36; ++j) acc[i][j] = 0.f;

    float4 qreg;
    float4 wreg[5];

    auto LOAD = [&](int k0) {
        qreg = *(const float4*)&query[(size_t)(row0 + sr) * 256 + k0 + sk];
#pragma unroll
        for (int j = 0; j < 5; ++j) {
            if (wok[j]) {
                wreg[j] = (wc4[j] < 48)
                    ? *(const float4*)&Woff[(size_t)(k0 + wkk[j]) * 192 + 4 * wc4[j]]
                    : *(const float4*)&Wattn[(size_t)(k0 + wkk[j]) * 96 + 4 * (wc4[j] - 48)];
            }
        }
    };
    auto STORE = [&]() {
        Qs[(sk + 0) * 68 + sr] = qreg.x;
        Qs[(sk + 1) * 68 + sr] = qreg.y;
        Qs[(sk + 2) * 68 + sr] = qreg.z;
        Qs[(sk + 3) * 68 + sr] = qreg.w;
#pragma unroll
        for (int j = 0; j < 5; ++j)
            if (wok[j]) *(float4*)&WL[wkk[j] * 288 + 4 * wc4[j]] = wreg[j];
    };

    LOAD(0);
    for (int step = 0; step < 16; ++step) {
        STORE();
        __syncthreads();
        if (step < 15) LOAD((step + 1) * 16);

#pragma unroll
        for (int kk = 0; kk < 16; ++kk) {
            const float a0 = Qs[kk * 68 + r0];
            const float a1 = Qs[kk * 68 + r0 + 32];
            const float* wo = &WL[kk * 288 + h * 24];
            const float* wa = &WL[kk * 288 + 192 + h * 12];
#pragma unroll
            for (int u = 0; u < 6; ++u) {
                const float4 w4 = *(const float4*)&wo[4 * u];
                acc[0][4 * u + 0] = fmaf(a0, w4.x, acc[0][4 * u + 0]);
                acc[0][4 * u + 1] = fmaf(a0, w4.y, acc[0][4 * u + 1]);
                acc[0][4 * u + 2] = fmaf(a0, w4.z, acc[0][4 * u + 2]);
                acc[0][4 * u + 3] = fmaf(a0, w4.w, acc[0][4 * u + 3]);
                acc[1][4 * u + 0] = fmaf(a1, w4.x, acc[1][4 * u + 0]);
                acc[1][4 * u + 1] = fmaf(a1, w4.y, acc[1][4 * u + 1]);
                acc[1][4 * u + 2] = fmaf(a1, w4.z, acc[1][4 * u + 2]);
                acc[1][4 * u + 3] = fmaf(a1, w4.w, acc[1][4 * u + 3]);
            }
#pragma unroll
            for (int u = 0; u < 3; ++u) {
                const float4 w4 = *(const float4*)&wa[4 * u];
                acc[0][24 + 4 * u + 0] = fmaf(a0, w4.x, acc[0][24 + 4 * u + 0]);
                acc[0][24 + 4 * u + 1] = fmaf(a0, w4.y, acc[0][24 + 4 * u + 1]);
                acc[0][24 + 4 * u + 2] = fmaf(a0, w4.z, acc[0][24 + 4 * u + 2]);
                acc[0][24 + 4 * u + 3] = fmaf(a0, w4.w, acc[0][24 + 4 * u + 3]);
                acc[1][24 + 4 * u + 0] = fmaf(a1, w4.x, acc[1][24 + 4 * u + 0]);
                acc[1][24 + 4 * u + 1] = fmaf(a1, w4.y, acc[1][24 + 4 * u + 1]);
                acc[1][24 + 4 * u + 2] = fmaf(a1, w4.z, acc[1][24 + 4 * u + 2]);
                acc[1][24 + 4 * u + 3] = fmaf(a1, w4.w, acc[1][24 + 4 * u + 3]);
            }
        }
        __syncthreads();
    }

    // ---- epilogue (registers only) ----
#pragma unroll
    for (int i = 0; i < 2; ++i) {
        const int row = row0 + r0 + 32 * i;
        float* lg = acc[i];

#pragma unroll
        for (int j = 0; j < 24; ++j) lg[j] += boff[h * 24 + j];
#pragma unroll
        for (int j = 0; j < 12; ++j) lg[24 + j] += battn[h * 12 + j];

        float m = lg[24];
#pragma unroll
        for (int j = 1; j < 12; ++j) m = fmaxf(m, lg[24 + j]);
        float s = 0.f;
        float al[12];
#pragma unroll
        for (int j = 0; j < 12; ++j) { al[j] = __expf(lg[24 + j] - m); s += al[j]; }
        const float inv = 1.f / s;

        const float refx = ref[(size_t)row * 2 + 0];
        const float refy = ref[(size_t)row * 2 + 1];

        float outv[36];
#pragma unroll
        for (int l = 0; l < 3; ++l) {
            const float Wl = (l == 0) ? 100.f : (l == 1) ? 50.f : 25.f;
#pragma unroll
            for (int p = 0; p < 4; ++p) {
                const int j = l * 4 + p;
                const float ox = 0.5f * tanh_fast(lg[l * 8 + p * 2 + 0]);
                const float oy = 0.5f * tanh_fast(lg[l * 8 + p * 2 + 1]);
                outv[3 * j + 0] = (refx + ox) * Wl - 0.5f;
                outv[3 * j + 1] = (refy + oy) * Wl - 0.5f;
                outv[3 * j + 2] = al[j] * inv;
            }
        }

        float4* pp = (float4*)(params + (size_t)row * 288 + h * 36);
#pragma unroll
        for (int u = 0; u < 9; ++u)
            pp[u] = make_float4(outv[4 * u + 0], outv[4 * u + 1],
                                outv[4 * u + 2], outv[4 * u + 3]);
    }
}

// ---------------------------------------------------------------------------
// K3: sampler.  ONE WAVE = ONE QUERY.
// ---------------------------------------------------------------------------
__global__ __launch_bounds__(256) void sample_kernel(
    const float* __restrict__ params,
    const unsigned short* __restrict__ v0,
    const unsigned short* __restrict__ v1,
    const unsigned short* __restrict__ v2,
    float* __restrict__ outp)
{
    const int tid  = threadIdx.x;
    const int lane = tid & 63;
    const int q    = blockIdx.x * 4 + (tid >> 6);
    const int h    = lane >> 3;
    const int qd   = lane & 7;
    const int b    = q / QLEN;

    const float4* pp = (const float4*)(params + (size_t)q * 288 + h * 36);
    float f[36];
#pragma unroll
    for (int i = 0; i < 9; ++i) {
        const float4 v = pp[i];
        f[4 * i + 0] = v.x; f[4 * i + 1] = v.y;
        f[4 * i + 2] = v.z; f[4 * i + 3] = v.w;
    }

    float o0 = 0.f, o1 = 0.f, o2 = 0.f, o3 = 0.f;

#pragma unroll
    for (int l = 0; l < 3; ++l) {
        const int Wl = (l == 0) ? 100 : (l == 1) ? 50 : 25;
        const int Hl = Wl;
        const unsigned short* vb =
            (l == 0) ? v0 + (size_t)b * 10000 * 256 :
            (l == 1) ? v1 + (size_t)b * 2500  * 256 :
                       v2 + (size_t)b * 625   * 256;

        int   cidx[16];
        float cwt[16];
#pragma unroll
        for (int p = 0; p < 4; ++p) {
            const int j = l * 4 + p;
            const float x  = f[3 * j + 0];
            const float y  = f[3 * j + 1];
            const float aw = f[3 * j + 2];
            const float xf = floorf(x), yf = floorf(y);
            const int   x0i = (int)xf, y0i = (int)yf;
            const float wx = x - xf, wy = y - yf;
#pragma unroll
            for (int cy = 0; cy < 2; ++cy) {
#pragma unroll
                for (int cx = 0; cx < 2; ++cx) {
                    const int xi = x0i + cx, yi = y0i + cy;
                    const bool valid =
                        (xi >= 0) & (xi < Wl) & (yi >= 0) & (yi < Hl);
                    const int xc = min(max(xi, 0), Wl - 1);
                    const int yc = min(max(yi, 0), Hl - 1);
                    const float w = aw * (cx ? wx : 1.f - wx)
                                       * (cy ? wy : 1.f - wy);
                    cidx[p * 4 + cy * 2 + cx] = yc * Wl + xc;
                    cwt [p * 4 + cy * 2 + cx] = valid ? w : 0.f;
                }
            }
        }
#pragma unroll
        for (int k = 0; k < 16; ++k) {
            const ushort4 u = *(const ushort4*)(vb +
                (size_t)cidx[k] * 256 + h * 32 + qd * 4);
            const float cw = cwt[k];
            o0 = fmaf(cw, bf2f(u.x), o0);
            o1 = fmaf(cw, bf2f(u.y), o1);
            o2 = fmaf(cw, bf2f(u.z), o2);
            o3 = fmaf(cw, bf2f(u.w), o3);
        }
    }

    *(float4*)(outp + (size_t)q * 256 + lane * 4) = make_float4(o0, o1, o2, o3);
}

// ---------------------------------------------------------------------------
// K4: output projection (in-place on d_out).  64 rows/block, 625 blocks,
// software-pipelined staging.
// ---------------------------------------------------------------------------
__global__ __launch_bounds__(256) void outproj_kernel(
    const float* __restrict__ A, const float* __restrict__ Wo,
    const float* __restrict__ bo, float* __restrict__ out)
{
    __shared__ float As[16 * 68];    // [kk][r]
    __shared__ float Ws[16 * 256];

    const int row0 = blockIdx.x * 64;
    const int tid  = threadIdx.x;
    const int tp   = tid >> 5;
    const int tc   = tid & 31;

    const int sr  = tid >> 2;         // 0..63
    const int sk  = (tid & 3) * 4;    // 0,4,8,12
    const int wkk = tid >> 6;         // + 4j
    const int wc4 = (tid & 63) * 4;

    float acc[8][8];
#pragma unroll
    for (int i = 0; i < 8; ++i)
#pragma unroll
        for (int j = 0; j < 8; ++j) acc[i][j] = 0.f;

    float4 areg;
    float4 wreg[4];

    auto LOAD = [&](int k0) {
        areg = *(const float4*)&A[(size_t)(row0 + sr) * 256 + k0 + sk];
#pragma unroll
        for (int j = 0; j < 4; ++j)
            wreg[j] = *(const float4*)&Wo[(size_t)(k0 + wkk + 4 * j) * 256 + wc4];
    };
    auto STORE = [&]() {
        As[(sk + 0) * 68 + sr] = areg.x;
        As[(sk + 1) * 68 + sr] = areg.y;
        As[(sk + 2) * 68 + sr] = areg.z;
        As[(sk + 3) * 68 + sr] = areg.w;
#pragma unroll
        for (int j = 0; j < 4; ++j)
            *(float4*)&Ws[(wkk + 4 * j) * 256 + wc4] = wreg[j];
    };

    LOAD(0);
    for (int step = 0; step < 16; ++step) {
        STORE();
        __syncthreads();
        if (step < 15) LOAD((step + 1) * 16);

#pragma unroll
        for (int kk = 0; kk < 16; ++kk) {
            const float4 a0 = *(const float4*)&As[kk * 68 + tp * 8];
            const float4 a1 = *(const float4*)&As[kk * 68 + tp * 8 + 4];
            const float a[8] = {a0.x, a0.y, a0.z, a0.w, a1.x, a1.y, a1.z, a1.w};
            float w[8];
#pragma unroll
            for (int jj = 0; jj < 4; ++jj) {
                const float2 wv = *(const float2*)&Ws[kk * 256 + 2 * tc + 64 * jj];
                w[2 * jj]     = wv.x;
                w[2 * jj + 1] = wv.y;
            }
#pragma unroll
            for (int i = 0; i < 8; ++i)
#pragma unroll
                for (int j = 0; j < 8; ++j)
                    acc[i][j] = fmaf(a[i], w[j], acc[i][j]);
        }
        __syncthreads();
    }

    float bb[8];
#pragma unroll
    for (int jj = 0; jj < 4; ++jj) {
        const float2 bvv = *(const float2*)&bo[2 * tc + 64 * jj];
        bb[2 * jj]     = bvv.x;
        bb[2 * jj + 1] = bvv.y;
    }

#pragma unroll
    for (int i = 0; i < 8; ++i) {
        const int r = row0 + tp * 8 + i;
        unsigned long long base = (unsigned long long)r * 256;
#pragma unroll
        for (int jj = 0; jj < 4; ++jj) {
            out[base + 2 * tc + 64 * jj + 0] = acc[i][2 * jj]     + bb[2 * jj];
            out[base + 2 * tc + 64 * jj + 1] = acc[i][2 * jj + 1] + bb[2 * jj + 1];
        }
    }
}

// ---------------------------------------------------------------------------
extern "C" void kernel_launch(void* const* d_in, const int* in_sizes, int n_in,
                              void* d_out, int out_size, void* d_ws, size_t ws_size,
                              hipStream_t stream)
{
    const float* query  = (const float*)d_in[0];
    const float* value0 = (const float*)d_in[1];
    const float* value1 = (const float*)d_in[2];
    const float* value2 = (const float*)d_in[3];
    const float* refpts = (const float*)d_in[4];
    const float* Woff   = (const float*)d_in[5];
    const float* boff   = (const float*)d_in[6];
    const float* Wattn  = (const float*)d_in[7];
    const float* battn  = (const float*)d_in[8];
    const float* Wval   = (const float*)d_in[9];
    const float* bval   = (const float*)d_in[10];
    const float* Wout   = (const float*)d_in[11];
    const float* bout   = (const float*)d_in[12];
    float* out = (float*)d_out;

    // workspace: params (46.08 MB) + v bf16 (26.88 MB) = 72.96 MB
    float*          params = (float*)d_ws;
    unsigned short* v0 = (unsigned short*)(params + (size_t)NQ * 288);
    unsigned short* v1 = v0 + (size_t)BATCH * 10000 * 256;
    unsigned short* v2 = v1 + (size_t)BATCH * 2500  * 256;
    float*          outp = out;   // outproj is in-place

    vproj_kernel<<<dim3(207, BATCH), 256, 0, stream>>>(
        value0, value1, value2, Wval, bval, v0, v1, v2);

    qparam_kernel<<<NQ / 64, 256, 0, stream>>>(query, refpts, Woff, boff,
                                               Wattn, battn, params);

    sample_kernel<<<NQ / 4, 256, 0, stream>>>(params, v0, v1, v2, outp);

    outproj_kernel<<<NQ / 64, 256, 0, stream>>>(outp, Wout, bout, out);
}

// Round 7
// 402.490 us; speedup vs baseline: 1.2297x; 1.2297x over previous
//
#include <hip/hip_runtime.h>
#include <math.h>

#define DMODEL 256
#define NHEAD 8
#define NLVL 3
#define NPTS 4
#define HDIM 32
#define QLEN 10000
#define BATCH 4
#define NQ (BATCH * QLEN)

typedef __attribute__((ext_vector_type(8))) short bf16x8;
typedef __attribute__((ext_vector_type(4))) float f32x4;

__device__ __forceinline__ float tanh_fast(float x)
{
    const float ax = fabsf(x);
    const float e  = __expf(-2.f * ax);
    const float t  = (1.f - e) / (1.f + e);
    return copysignf(t, x);
}

__device__ __forceinline__ unsigned short f2bf(float f)
{
    unsigned int u = __float_as_uint(f);
    u = (u + 0x7FFFu + ((u >> 16) & 1u)) >> 16;
    return (unsigned short)u;
}

__device__ __forceinline__ float bf2f(unsigned short s)
{
    return __uint_as_float(((unsigned int)s) << 16);
}

// ---------------------------------------------------------------------------
// K1: value projection -> bf16, all 3 levels in one grid, direct staging.
// ---------------------------------------------------------------------------
__global__ __launch_bounds__(256) void vproj_kernel(
    const float* __restrict__ feat0, const float* __restrict__ feat1,
    const float* __restrict__ feat2, const float* __restrict__ Wv,
    const float* __restrict__ bv,
    unsigned short* __restrict__ v0, unsigned short* __restrict__ v1,
    unsigned short* __restrict__ v2)
{
    __shared__ float As[16 * 64];    // [kk][pos]
    __shared__ float Ws[16 * 256];   // [kk][col]

    const int bx = blockIdx.x;
    const int b  = blockIdx.y;

    const float* feat;
    unsigned short* vout;
    int HW, pos0;
    if (bx < 157)      { feat = feat0; vout = v0; HW = 10000; pos0 = bx * 64; }
    else if (bx < 197) { feat = feat1; vout = v1; HW = 2500;  pos0 = (bx - 157) * 64; }
    else               { feat = feat2; vout = v2; HW = 625;   pos0 = (bx - 197) * 64; }

    const int tid  = threadIdx.x;
    const int tp   = tid >> 5;
    const int tc   = tid & 31;

    const int ap   = tid & 63;            // position within tile
    const int ak   = tid >> 6;            // base kk (stride 4)
    const int wkk  = tid >> 6;
    const int wc4  = (tid & 63) * 4;

    float acc[8][8];
#pragma unroll
    for (int i = 0; i < 8; ++i)
#pragma unroll
        for (int j = 0; j < 8; ++j) acc[i][j] = 0.f;

    const float* fb = feat + (size_t)b * DMODEL * HW;
    const bool pvalid = (pos0 + ap) < HW;

    for (int k0 = 0; k0 < 256; k0 += 16) {
#pragma unroll
        for (int it = 0; it < 4; ++it) {
            const int kk = ak + it * 4;
            As[kk * 64 + ap] = pvalid ? fb[(size_t)(k0 + kk) * HW + pos0 + ap] : 0.f;
        }
#pragma unroll
        for (int j = 0; j < 4; ++j)
            *(float4*)&Ws[(wkk + 4 * j) * 256 + wc4] =
                *(const float4*)&Wv[(size_t)(k0 + wkk + 4 * j) * 256 + wc4];
        __syncthreads();

#pragma unroll
        for (int kk = 0; kk < 16; ++kk) {
            const float4 a0 = *(const float4*)&As[kk * 64 + tp * 8];
            const float4 a1 = *(const float4*)&As[kk * 64 + tp * 8 + 4];
            const float a[8] = {a0.x, a0.y, a0.z, a0.w, a1.x, a1.y, a1.z, a1.w};
            float w[8];
#pragma unroll
            for (int jj = 0; jj < 4; ++jj) {
                const float2 wv = *(const float2*)&Ws[kk * 256 + 2 * tc + 64 * jj];
                w[2 * jj]     = wv.x;
                w[2 * jj + 1] = wv.y;
            }
#pragma unroll
            for (int i = 0; i < 8; ++i)
#pragma unroll
                for (int j = 0; j < 8; ++j)
                    acc[i][j] = fmaf(a[i], w[j], acc[i][j]);
        }
        __syncthreads();
    }

    float bb[8];
#pragma unroll
    for (int jj = 0; jj < 4; ++jj) {
        const float2 bvv = *(const float2*)&bv[2 * tc + 64 * jj];
        bb[2 * jj]     = bvv.x;
        bb[2 * jj + 1] = bvv.y;
    }

    unsigned short* vb = vout + (size_t)b * HW * 256;
#pragma unroll
    for (int i = 0; i < 8; ++i) {
        const int p = pos0 + tp * 8 + i;
        if (p < HW) {
            unsigned int* vp = (unsigned int*)(vb + (size_t)p * 256);
#pragma unroll
            for (int jj = 0; jj < 4; ++jj) {
                const unsigned int lo = f2bf(acc[i][2 * jj]     + bb[2 * jj]);
                const unsigned int hi = f2bf(acc[i][2 * jj + 1] + bb[2 * jj + 1]);
                vp[tc + 32 * jj] = lo | (hi << 16);
            }
        }
    }
}

// ---------------------------------------------------------------------------
// K2: query-side GEMM + epilogue.  64 rows/block (625 blocks), 256 threads,
// thread = (r0, h) owns rows {r0, r0+32} with acc[2][36].  Linear LDS W
// layout, DIRECT staging (no reg pipeline).  Epilogue fully in registers.
// ---------------------------------------------------------------------------
__global__ __launch_bounds__(256) void qparam_kernel(
    const float* __restrict__ query, const float* __restrict__ ref,
    const float* __restrict__ Woff, const float* __restrict__ boff,
    const float* __restrict__ Wattn, const float* __restrict__ battn,
    float* __restrict__ params)
{
    __shared__ float Qs[16 * 68];    // [kk][r], stride 68
    __shared__ float WL[16 * 288];   // [kk][col] linear

    const int row0 = blockIdx.x * 64;
    const int tid  = threadIdx.x;
    const int h    = tid & 7;
    const int r0   = tid >> 3;       // 0..31

    const int sr = tid >> 2;          // 0..63
    const int sk = (tid & 3) * 4;     // 0,4,8,12

    int wkk[5], wc4[5];
    bool wok[5];
#pragma unroll
    for (int j = 0; j < 5; ++j) {
        const int g = tid + j * 256;
        wok[j] = (g < 1152);
        wkk[j] = g / 72;
        wc4[j] = g - wkk[j] * 72;
    }

    float acc[2][36];
#pragma unroll
    for (int i = 0; i < 2; ++i)
#pragma unroll
        for (int j = 0; j < 36; ++j) acc[i][j] = 0.f;

    for (int k0 = 0; k0 < 256; k0 += 16) {
        {
            const float4 qv =
                *(const float4*)&query[(size_t)(row0 + sr) * 256 + k0 + sk];
            Qs[(sk + 0) * 68 + sr] = qv.x;
            Qs[(sk + 1) * 68 + sr] = qv.y;
            Qs[(sk + 2) * 68 + sr] = qv.z;
            Qs[(sk + 3) * 68 + sr] = qv.w;
        }
#pragma unroll
        for (int j = 0; j < 5; ++j) {
            if (wok[j]) {
                const float4 wv = (wc4[j] < 48)
                    ? *(const float4*)&Woff[(size_t)(k0 + wkk[j]) * 192 + 4 * wc4[j]]
                    : *(const float4*)&Wattn[(size_t)(k0 + wkk[j]) * 96 + 4 * (wc4[j] - 48)];
                *(float4*)&WL[wkk[j] * 288 + 4 * wc4[j]] = wv;
            }
        }
        __syncthreads();

#pragma unroll
        for (int kk = 0; kk < 16; ++kk) {
            const float a0 = Qs[kk * 68 + r0];
            const float a1 = Qs[kk * 68 + r0 + 32];
            const float* wo = &WL[kk * 288 + h * 24];
            const float* wa = &WL[kk * 288 + 192 + h * 12];
#pragma unroll
            for (int u = 0; u < 6; ++u) {
                const float4 w4 = *(const float4*)&wo[4 * u];
                acc[0][4 * u + 0] = fmaf(a0, w4.x, acc[0][4 * u + 0]);
                acc[0][4 * u + 1] = fmaf(a0, w4.y, acc[0][4 * u + 1]);
                acc[0][4 * u + 2] = fmaf(a0, w4.z, acc[0][4 * u + 2]);
                acc[0][4 * u + 3] = fmaf(a0, w4.w, acc[0][4 * u + 3]);
                acc[1][4 * u + 0] = fmaf(a1, w4.x, acc[1][4 * u + 0]);
                acc[1][4 * u + 1] = fmaf(a1, w4.y, acc[1][4 * u + 1]);
                acc[1][4 * u + 2] = fmaf(a1, w4.z, acc[1][4 * u + 2]);
                acc[1][4 * u + 3] = fmaf(a1, w4.w, acc[1][4 * u + 3]);
            }
#pragma unroll
            for (int u = 0; u < 3; ++u) {
                const float4 w4 = *(const float4*)&wa[4 * u];
                acc[0][24 + 4 * u + 0] = fmaf(a0, w4.x, acc[0][24 + 4 * u + 0]);
                acc[0][24 + 4 * u + 1] = fmaf(a0, w4.y, acc[0][24 + 4 * u + 1]);
                acc[0][24 + 4 * u + 2] = fmaf(a0, w4.z, acc[0][24 + 4 * u + 2]);
                acc[0][24 + 4 * u + 3] = fmaf(a0, w4.w, acc[0][24 + 4 * u + 3]);
                acc[1][24 + 4 * u + 0] = fmaf(a1, w4.x, acc[1][24 + 4 * u + 0]);
                acc[1][24 + 4 * u + 1] = fmaf(a1, w4.y, acc[1][24 + 4 * u + 1]);
                acc[1][24 + 4 * u + 2] = fmaf(a1, w4.z, acc[1][24 + 4 * u + 2]);
                acc[1][24 + 4 * u + 3] = fmaf(a1, w4.w, acc[1][24 + 4 * u + 3]);
            }
        }
        __syncthreads();
    }

    // ---- epilogue (registers only) ----
#pragma unroll
    for (int i = 0; i < 2; ++i) {
        const int row = row0 + r0 + 32 * i;
        float* lg = acc[i];

#pragma unroll
        for (int j = 0; j < 24; ++j) lg[j] += boff[h * 24 + j];
#pragma unroll
        for (int j = 0; j < 12; ++j) lg[24 + j] += battn[h * 12 + j];

        float m = lg[24];
#pragma unroll
        for (int j = 1; j < 12; ++j) m = fmaxf(m, lg[24 + j]);
        float s = 0.f;
        float al[12];
#pragma unroll
        for (int j = 0; j < 12; ++j) { al[j] = __expf(lg[24 + j] - m); s += al[j]; }
        const float inv = 1.f / s;

        const float refx = ref[(size_t)row * 2 + 0];
        const float refy = ref[(size_t)row * 2 + 1];

        float outv[36];
#pragma unroll
        for (int l = 0; l < 3; ++l) {
            const float Wl = (l == 0) ? 100.f : (l == 1) ? 50.f : 25.f;
#pragma unroll
            for (int p = 0; p < 4; ++p) {
                const int j = l * 4 + p;
                const float ox = 0.5f * tanh_fast(lg[l * 8 + p * 2 + 0]);
                const float oy = 0.5f * tanh_fast(lg[l * 8 + p * 2 + 1]);
                outv[3 * j + 0] = (refx + ox) * Wl - 0.5f;
                outv[3 * j + 1] = (refy + oy) * Wl - 0.5f;
                outv[3 * j + 2] = al[j] * inv;
            }
        }

        float4* pp = (float4*)(params + (size_t)row * 288 + h * 36);
#pragma unroll
        for (int u = 0; u < 9; ++u)
            pp[u] = make_float4(outv[4 * u + 0], outv[4 * u + 1],
                                outv[4 * u + 2], outv[4 * u + 3]);
    }
}

// ---------------------------------------------------------------------------
// K3: sampler.  ONE WAVE = ONE QUERY.  Output written as bf16 (feeds MFMA
// outproj).
// ---------------------------------------------------------------------------
__global__ __launch_bounds__(256) void sample_kernel(
    const float* __restrict__ params,
    const unsigned short* __restrict__ v0,
    const unsigned short* __restrict__ v1,
    const unsigned short* __restrict__ v2,
    unsigned short* __restrict__ outp)
{
    const int tid  = threadIdx.x;
    const int lane = tid & 63;
    const int q    = blockIdx.x * 4 + (tid >> 6);
    const int h    = lane >> 3;
    const int qd   = lane & 7;
    const int b    = q / QLEN;

    const float4* pp = (const float4*)(params + (size_t)q * 288 + h * 36);
    float f[36];
#pragma unroll
    for (int i = 0; i < 9; ++i) {
        const float4 v = pp[i];
        f[4 * i + 0] = v.x; f[4 * i + 1] = v.y;
        f[4 * i + 2] = v.z; f[4 * i + 3] = v.w;
    }

    float o0 = 0.f, o1 = 0.f, o2 = 0.f, o3 = 0.f;

#pragma unroll
    for (int l = 0; l < 3; ++l) {
        const int Wl = (l == 0) ? 100 : (l == 1) ? 50 : 25;
        const int Hl = Wl;
        const unsigned short* vb =
            (l == 0) ? v0 + (size_t)b * 10000 * 256 :
            (l == 1) ? v1 + (size_t)b * 2500  * 256 :
                       v2 + (size_t)b * 625   * 256;

        int   cidx[16];
        float cwt[16];
#pragma unroll
        for (int p = 0; p < 4; ++p) {
            const int j = l * 4 + p;
            const float x  = f[3 * j + 0];
            const float y  = f[3 * j + 1];
            const float aw = f[3 * j + 2];
            const float xf = floorf(x), yf = floorf(y);
            const int   x0i = (int)xf, y0i = (int)yf;
            const float wx = x - xf, wy = y - yf;
#pragma unroll
            for (int cy = 0; cy < 2; ++cy) {
#pragma unroll
                for (int cx = 0; cx < 2; ++cx) {
                    const int xi = x0i + cx, yi = y0i + cy;
                    const bool valid =
                        (xi >= 0) & (xi < Wl) & (yi >= 0) & (yi < Hl);
                    const int xc = min(max(xi, 0), Wl - 1);
                    const int yc = min(max(yi, 0), Hl - 1);
                    const float w = aw * (cx ? wx : 1.f - wx)
                                       * (cy ? wy : 1.f - wy);
                    cidx[p * 4 + cy * 2 + cx] = yc * Wl + xc;
                    cwt [p * 4 + cy * 2 + cx] = valid ? w : 0.f;
                }
            }
        }
#pragma unroll
        for (int k = 0; k < 16; ++k) {
            const ushort4 u = *(const ushort4*)(vb +
                (size_t)cidx[k] * 256 + h * 32 + qd * 4);
            const float cw = cwt[k];
            o0 = fmaf(cw, bf2f(u.x), o0);
            o1 = fmaf(cw, bf2f(u.y), o1);
            o2 = fmaf(cw, bf2f(u.z), o2);
            o3 = fmaf(cw, bf2f(u.w), o3);
        }
    }

    unsigned int lo = (unsigned int)f2bf(o0) | ((unsigned int)f2bf(o1) << 16);
    unsigned int hi = (unsigned int)f2bf(o2) | ((unsigned int)f2bf(o3) << 16);
    *(uint2*)(outp + (size_t)q * 256 + lane * 4) = make_uint2(lo, hi);
}

// ---------------------------------------------------------------------------
// K4a: transpose+convert W_out [k][n] fp32 -> WoT [n][k] bf16 (once).
// ---------------------------------------------------------------------------
__global__ __launch_bounds__(256) void wconv_kernel(
    const float* __restrict__ Wo, unsigned short* __restrict__ WoT)
{
    __shared__ float T[64][65];
    const int tid = threadIdx.x;
    const int bk  = (blockIdx.x & 3) * 64;
    const int bn  = (blockIdx.x >> 2) * 64;
    const int tn  = tid & 63;
    const int tk  = tid >> 6;     // 0..3
#pragma unroll
    for (int it = 0; it < 16; ++it) {
        const int k = tk + it * 4;
        T[k][tn] = Wo[(size_t)(bk + k) * 256 + bn + tn];
    }
    __syncthreads();
    const int tk2 = tid & 63;
    const int tn2 = tid >> 6;
#pragma unroll
    for (int it = 0; it < 16; ++it) {
        const int n = tn2 + it * 4;
        WoT[(size_t)(bn + n) * 256 + bk + tk2] = f2bf(T[tk2][n]);
    }
}

// ---------------------------------------------------------------------------
// K4b: output projection via bf16 MFMA.  64 rows x 256 cols per block,
// 4 waves; wave w owns cols [64w,64w+64): 4x4 fragments of 16x16x32.
// A (bf16 sampled output) and B (WoT) fragments read directly from global
// (L1/L2 resident).  Fragment mapping (m89-verified family):
//   lane = c + 16g;  a[j]=A[c][8g+j], b[j]=B[8g+j][c], D[4g+j][c].
// ---------------------------------------------------------------------------
__global__ __launch_bounds__(256) void outproj_kernel(
    const unsigned short* __restrict__ A, const unsigned short* __restrict__ WoT,
    const float* __restrict__ bo, float* __restrict__ out)
{
    const int tid  = threadIdx.x;
    const int wave = tid >> 6;
    const int lane = tid & 63;
    const int c    = lane & 15;
    const int g    = lane >> 4;
    const int row0 = blockIdx.x * 64;
    const int n0   = wave * 64;

    f32x4 acc[4][4];
#pragma unroll
    for (int mt = 0; mt < 4; ++mt)
#pragma unroll
        for (int nt = 0; nt < 4; ++nt)
            acc[mt][nt] = (f32x4){0.f, 0.f, 0.f, 0.f};

    const unsigned short* Abase = A   + (size_t)(row0 + c) * 256 + 8 * g;
    const unsigned short* Bbase = WoT + (size_t)(n0   + c) * 256 + 8 * g;

#pragma unroll
    for (int ks = 0; ks < 8; ++ks) {
        bf16x8 a[4], b[4];
#pragma unroll
        for (int t = 0; t < 4; ++t) {
            a[t] = *(const bf16x8*)(Abase + (size_t)t * 16 * 256 + ks * 32);
            b[t] = *(const bf16x8*)(Bbase + (size_t)t * 16 * 256 + ks * 32);
        }
#pragma unroll
        for (int mt = 0; mt < 4; ++mt)
#pragma unroll
            for (int nt = 0; nt < 4; ++nt)
                acc[mt][nt] = __builtin_amdgcn_mfma_f32_16x16x32_bf16(
                    a[mt], b[nt], acc[mt][nt], 0, 0, 0);
    }

#pragma unroll
    for (int nt = 0; nt < 4; ++nt) {
        const int col  = n0 + nt * 16 + c;
        const float bias = bo[col];
#pragma unroll
        for (int mt = 0; mt < 4; ++mt) {
#pragma unroll
            for (int j = 0; j < 4; ++j) {
                const int row = row0 + mt * 16 + g * 4 + j;
                out[(size_t)row * 256 + col] = acc[mt][nt][j] + bias;
            }
        }
    }
}

// ---------------------------------------------------------------------------
extern "C" void kernel_launch(void* const* d_in, const int* in_sizes, int n_in,
                              void* d_out, int out_size, void* d_ws, size_t ws_size,
                              hipStream_t stream)
{
    const float* query  = (const float*)d_in[0];
    const float* value0 = (const float*)d_in[1];
    const float* value1 = (const float*)d_in[2];
    const float* value2 = (const float*)d_in[3];
    const float* refpts = (const float*)d_in[4];
    const float* Woff   = (const float*)d_in[5];
    const float* boff   = (const float*)d_in[6];
    const float* Wattn  = (const float*)d_in[7];
    const float* battn  = (const float*)d_in[8];
    const float* Wval   = (const float*)d_in[9];
    const float* bval   = (const float*)d_in[10];
    const float* Wout   = (const float*)d_in[11];
    const float* bout   = (const float*)d_in[12];
    float* out = (float*)d_out;

    // workspace layout:
    //   params : NQ*288 f32   = 46.08 MB
    //   v0/v1/v2 bf16         = 26.88 MB
    //   A_bf   : NQ*256 bf16  = 20.48 MB
    //   WoT    : 256*256 bf16 =  0.13 MB       total ~93.6 MB
    float*          params = (float*)d_ws;
    unsigned short* v0   = (unsigned short*)(params + (size_t)NQ * 288);
    unsigned short* v1   = v0 + (size_t)BATCH * 10000 * 256;
    unsigned short* v2   = v1 + (size_t)BATCH * 2500  * 256;
    unsigned short* A_bf = v2 + (size_t)BATCH * 625   * 256;
    unsigned short* WoT  = A_bf + (size_t)NQ * 256;

    vproj_kernel<<<dim3(207, BATCH), 256, 0, stream>>>(
        value0, value1, value2, Wval, bval, v0, v1, v2);

    qparam_kernel<<<NQ / 64, 256, 0, stream>>>(query, refpts, Woff, boff,
                                               Wattn, battn, params);

    wconv_kernel<<<16, 256, 0, stream>>>(Wout, WoT);

    sample_kernel<<<NQ / 4, 256, 0, stream>>>(params, v0, v1, v2, A_bf);

    outproj_kernel<<<NQ / 64, 256, 0, stream>>>(A_bf, WoT, bout, out);
}

// Round 8
// 384.818 us; speedup vs baseline: 1.2862x; 1.0459x over previous
//
#include <hip/hip_runtime.h>
#include <math.h>

#define DMODEL 256
#define NHEAD 8
#define NLVL 3
#define NPTS 4
#define HDIM 32
#define QLEN 10000
#define BATCH 4
#define NQ (BATCH * QLEN)

typedef __attribute__((ext_vector_type(8))) short bf16x8;
typedef __attribute__((ext_vector_type(4))) float f32x4;

__device__ __forceinline__ float tanh_fast(float x)
{
    const float ax = fabsf(x);
    const float e  = __expf(-2.f * ax);
    const float t  = (1.f - e) / (1.f + e);
    return copysignf(t, x);
}

__device__ __forceinline__ unsigned short f2bf(float f)
{
    unsigned int u = __float_as_uint(f);
    u = (u + 0x7FFFu + ((u >> 16) & 1u)) >> 16;
    return (unsigned short)u;
}

__device__ __forceinline__ float bf2f(unsigned short s)
{
    return __uint_as_float(((unsigned int)s) << 16);
}

// ---------------------------------------------------------------------------
// K1: value projection -> bf16, all 3 levels in one grid, direct staging.
// ---------------------------------------------------------------------------
__global__ __launch_bounds__(256) void vproj_kernel(
    const float* __restrict__ feat0, const float* __restrict__ feat1,
    const float* __restrict__ feat2, const float* __restrict__ Wv,
    const float* __restrict__ bv,
    unsigned short* __restrict__ v0, unsigned short* __restrict__ v1,
    unsigned short* __restrict__ v2)
{
    __shared__ float As[16 * 64];    // [kk][pos]
    __shared__ float Ws[16 * 256];   // [kk][col]

    const int bx = blockIdx.x;
    const int b  = blockIdx.y;

    const float* feat;
    unsigned short* vout;
    int HW, pos0;
    if (bx < 157)      { feat = feat0; vout = v0; HW = 10000; pos0 = bx * 64; }
    else if (bx < 197) { feat = feat1; vout = v1; HW = 2500;  pos0 = (bx - 157) * 64; }
    else               { feat = feat2; vout = v2; HW = 625;   pos0 = (bx - 197) * 64; }

    const int tid  = threadIdx.x;
    const int tp   = tid >> 5;
    const int tc   = tid & 31;

    const int ap   = tid & 63;
    const int ak   = tid >> 6;
    const int wkk  = tid >> 6;
    const int wc4  = (tid & 63) * 4;

    float acc[8][8];
#pragma unroll
    for (int i = 0; i < 8; ++i)
#pragma unroll
        for (int j = 0; j < 8; ++j) acc[i][j] = 0.f;

    const float* fb = feat + (size_t)b * DMODEL * HW;
    const bool pvalid = (pos0 + ap) < HW;

    for (int k0 = 0; k0 < 256; k0 += 16) {
#pragma unroll
        for (int it = 0; it < 4; ++it) {
            const int kk = ak + it * 4;
            As[kk * 64 + ap] = pvalid ? fb[(size_t)(k0 + kk) * HW + pos0 + ap] : 0.f;
        }
#pragma unroll
        for (int j = 0; j < 4; ++j)
            *(float4*)&Ws[(wkk + 4 * j) * 256 + wc4] =
                *(const float4*)&Wv[(size_t)(k0 + wkk + 4 * j) * 256 + wc4];
        __syncthreads();

#pragma unroll
        for (int kk = 0; kk < 16; ++kk) {
            const float4 a0 = *(const float4*)&As[kk * 64 + tp * 8];
            const float4 a1 = *(const float4*)&As[kk * 64 + tp * 8 + 4];
            const float a[8] = {a0.x, a0.y, a0.z, a0.w, a1.x, a1.y, a1.z, a1.w};
            float w[8];
#pragma unroll
            for (int jj = 0; jj < 4; ++jj) {
                const float2 wv = *(const float2*)&Ws[kk * 256 + 2 * tc + 64 * jj];
                w[2 * jj]     = wv.x;
                w[2 * jj + 1] = wv.y;
            }
#pragma unroll
            for (int i = 0; i < 8; ++i)
#pragma unroll
                for (int j = 0; j < 8; ++j)
                    acc[i][j] = fmaf(a[i], w[j], acc[i][j]);
        }
        __syncthreads();
    }

    float bb[8];
#pragma unroll
    for (int jj = 0; jj < 4; ++jj) {
        const float2 bvv = *(const float2*)&bv[2 * tc + 64 * jj];
        bb[2 * jj]     = bvv.x;
        bb[2 * jj + 1] = bvv.y;
    }

    unsigned short* vb = vout + (size_t)b * HW * 256;
#pragma unroll
    for (int i = 0; i < 8; ++i) {
        const int p = pos0 + tp * 8 + i;
        if (p < HW) {
            unsigned int* vp = (unsigned int*)(vb + (size_t)p * 256);
#pragma unroll
            for (int jj = 0; jj < 4; ++jj) {
                const unsigned int lo = f2bf(acc[i][2 * jj]     + bb[2 * jj]);
                const unsigned int hi = f2bf(acc[i][2 * jj + 1] + bb[2 * jj + 1]);
                vp[tc + 32 * jj] = lo | (hi << 16);
            }
        }
    }
}

// ---------------------------------------------------------------------------
// K2a: weight prep (once).  blocks 0..287: split-transpose W_off|W_attn
// fp32 [k][288] -> WT_hi/WT_lo bf16 [n][k].  blocks 288..543: transpose
// W_out -> WoT bf16 [n][k].
// ---------------------------------------------------------------------------
__global__ __launch_bounds__(256) void wprep_kernel(
    const float* __restrict__ Woff, const float* __restrict__ Wattn,
    const float* __restrict__ Wout,
    unsigned short* __restrict__ WTh, unsigned short* __restrict__ WTl,
    unsigned short* __restrict__ WoT)
{
    const int k = threadIdx.x;
    const int n = blockIdx.x;
    if (n < 288) {
        const float w = (n < 192) ? Woff[(size_t)k * 192 + n]
                                  : Wattn[(size_t)k * 96 + (n - 192)];
        const unsigned short hi = f2bf(w);
        WTh[(size_t)n * 256 + k] = hi;
        WTl[(size_t)n * 256 + k] = f2bf(w - bf2f(hi));
    } else {
        const int nn = n - 288;
        WoT[(size_t)nn * 256 + k] = f2bf(Wout[(size_t)k * 256 + nn]);
    }
}

// ---------------------------------------------------------------------------
// K2b: query-side GEMM via bf16x3 MFMA (fp32-accurate).  1 wave/block,
// 16 query rows, acc f32x4[18] covers all 288 cols.  A-frags read from
// global query fp32 (hi/lo split in regs); B-frags from WT_hi/WT_lo
// ([n][k] bf16, same proven pattern as outproj).  Logits -> LDS -> register
// epilogue (softmax + tanh -> sampling params).
// ---------------------------------------------------------------------------
__global__ __launch_bounds__(64) void qparam_kernel(
    const float* __restrict__ query, const float* __restrict__ ref,
    const unsigned short* __restrict__ WTh, const unsigned short* __restrict__ WTl,
    const float* __restrict__ boff, const float* __restrict__ battn,
    float* __restrict__ params)
{
    __shared__ float LG[16][292];
    const int lane = threadIdx.x;
    const int c    = lane & 15;
    const int g    = lane >> 4;
    const int row0 = blockIdx.x * 16;

    f32x4 acc[18];
#pragma unroll
    for (int nt = 0; nt < 18; ++nt) acc[nt] = (f32x4){0.f, 0.f, 0.f, 0.f};

    const float* qrow = query + (size_t)(row0 + c) * 256 + 8 * g;

#pragma unroll
    for (int ks = 0; ks < 8; ++ks) {
        const float4 q0 = *(const float4*)(qrow + ks * 32);
        const float4 q1 = *(const float4*)(qrow + ks * 32 + 4);
        const float av[8] = {q0.x, q0.y, q0.z, q0.w, q1.x, q1.y, q1.z, q1.w};
        bf16x8 a_hi, a_lo;
#pragma unroll
        for (int j = 0; j < 8; ++j) {
            const unsigned short hi = f2bf(av[j]);
            a_hi[j] = (short)hi;
            a_lo[j] = (short)f2bf(av[j] - bf2f(hi));
        }
#pragma unroll
        for (int nt = 0; nt < 18; ++nt) {
            const size_t bo = (size_t)(nt * 16 + c) * 256 + ks * 32 + 8 * g;
            const bf16x8 b_hi = *(const bf16x8*)(WTh + bo);
            const bf16x8 b_lo = *(const bf16x8*)(WTl + bo);
            acc[nt] = __builtin_amdgcn_mfma_f32_16x16x32_bf16(a_hi, b_hi, acc[nt], 0, 0, 0);
            acc[nt] = __builtin_amdgcn_mfma_f32_16x16x32_bf16(a_lo, b_hi, acc[nt], 0, 0, 0);
            acc[nt] = __builtin_amdgcn_mfma_f32_16x16x32_bf16(a_hi, b_lo, acc[nt], 0, 0, 0);
        }
    }

    // D[4g+j][c] per 16-col tile -> LDS logits [row][col]
#pragma unroll
    for (int nt = 0; nt < 18; ++nt)
#pragma unroll
        for (int j = 0; j < 4; ++j)
            LG[4 * g + j][nt * 16 + c] = acc[nt][j];
    __syncthreads();

    // epilogue: 2 (row,h) pairs per lane
#pragma unroll
    for (int i = 0; i < 2; ++i) {
        const int pair = lane + 64 * i;
        const int rl   = pair >> 3;
        const int h    = pair & 7;
        const int row  = row0 + rl;

        float lg[36];
#pragma unroll
        for (int j = 0; j < 24; ++j) lg[j] = LG[rl][h * 24 + j] + boff[h * 24 + j];
#pragma unroll
        for (int j = 0; j < 12; ++j) lg[24 + j] = LG[rl][192 + h * 12 + j] + battn[h * 12 + j];

        float m = lg[24];
#pragma unroll
        for (int j = 1; j < 12; ++j) m = fmaxf(m, lg[24 + j]);
        float s = 0.f;
        float al[12];
#pragma unroll
        for (int j = 0; j < 12; ++j) { al[j] = __expf(lg[24 + j] - m); s += al[j]; }
        const float inv = 1.f / s;

        const float refx = ref[(size_t)row * 2 + 0];
        const float refy = ref[(size_t)row * 2 + 1];

        float outv[36];
#pragma unroll
        for (int l = 0; l < 3; ++l) {
            const float Wl = (l == 0) ? 100.f : (l == 1) ? 50.f : 25.f;
#pragma unroll
            for (int p = 0; p < 4; ++p) {
                const int j = l * 4 + p;
                const float ox = 0.5f * tanh_fast(lg[l * 8 + p * 2 + 0]);
                const float oy = 0.5f * tanh_fast(lg[l * 8 + p * 2 + 1]);
                outv[3 * j + 0] = (refx + ox) * Wl - 0.5f;
                outv[3 * j + 1] = (refy + oy) * Wl - 0.5f;
                outv[3 * j + 2] = al[j] * inv;
            }
        }

        float4* pp = (float4*)(params + (size_t)row * 288 + h * 36);
#pragma unroll
        for (int u = 0; u < 9; ++u)
            pp[u] = make_float4(outv[4 * u + 0], outv[4 * u + 1],
                                outv[4 * u + 2], outv[4 * u + 3]);
    }
}

// ---------------------------------------------------------------------------
// K3: sampler.  ONE WAVE = ONE QUERY.  Output bf16 (feeds MFMA outproj).
// ---------------------------------------------------------------------------
__global__ __launch_bounds__(256) void sample_kernel(
    const float* __restrict__ params,
    const unsigned short* __restrict__ v0,
    const unsigned short* __restrict__ v1,
    const unsigned short* __restrict__ v2,
    unsigned short* __restrict__ outp)
{
    const int tid  = threadIdx.x;
    const int lane = tid & 63;
    const int q    = blockIdx.x * 4 + (tid >> 6);
    const int h    = lane >> 3;
    const int qd   = lane & 7;
    const int b    = q / QLEN;

    const float4* pp = (const float4*)(params + (size_t)q * 288 + h * 36);
    float f[36];
#pragma unroll
    for (int i = 0; i < 9; ++i) {
        const float4 v = pp[i];
        f[4 * i + 0] = v.x; f[4 * i + 1] = v.y;
        f[4 * i + 2] = v.z; f[4 * i + 3] = v.w;
    }

    float o0 = 0.f, o1 = 0.f, o2 = 0.f, o3 = 0.f;

#pragma unroll
    for (int l = 0; l < 3; ++l) {
        const int Wl = (l == 0) ? 100 : (l == 1) ? 50 : 25;
        const int Hl = Wl;
        const unsigned short* vb =
            (l == 0) ? v0 + (size_t)b * 10000 * 256 :
            (l == 1) ? v1 + (size_t)b * 2500  * 256 :
                       v2 + (size_t)b * 625   * 256;

        int   cidx[16];
        float cwt[16];
#pragma unroll
        for (int p = 0; p < 4; ++p) {
            const int j = l * 4 + p;
            const float x  = f[3 * j + 0];
            const float y  = f[3 * j + 1];
            const float aw = f[3 * j + 2];
            const float xf = floorf(x), yf = floorf(y);
            const int   x0i = (int)xf, y0i = (int)yf;
            const float wx = x - xf, wy = y - yf;
#pragma unroll
            for (int cy = 0; cy < 2; ++cy) {
#pragma unroll
                for (int cx = 0; cx < 2; ++cx) {
                    const int xi = x0i + cx, yi = y0i + cy;
                    const bool valid =
                        (xi >= 0) & (xi < Wl) & (yi >= 0) & (yi < Hl);
                    const int xc = min(max(xi, 0), Wl - 1);
                    const int yc = min(max(yi, 0), Hl - 1);
                    const float w = aw * (cx ? wx : 1.f - wx)
                                       * (cy ? wy : 1.f - wy);
                    cidx[p * 4 + cy * 2 + cx] = yc * Wl + xc;
                    cwt [p * 4 + cy * 2 + cx] = valid ? w : 0.f;
                }
            }
        }
#pragma unroll
        for (int k = 0; k < 16; ++k) {
            const ushort4 u = *(const ushort4*)(vb +
                (size_t)cidx[k] * 256 + h * 32 + qd * 4);
            const float cw = cwt[k];
            o0 = fmaf(cw, bf2f(u.x), o0);
            o1 = fmaf(cw, bf2f(u.y), o1);
            o2 = fmaf(cw, bf2f(u.z), o2);
            o3 = fmaf(cw, bf2f(u.w), o3);
        }
    }

    unsigned int lo = (unsigned int)f2bf(o0) | ((unsigned int)f2bf(o1) << 16);
    unsigned int hi = (unsigned int)f2bf(o2) | ((unsigned int)f2bf(o3) << 16);
    *(uint2*)(outp + (size_t)q * 256 + lane * 4) = make_uint2(lo, hi);
}

// ---------------------------------------------------------------------------
// K4: output projection via bf16 MFMA (validated R7).
// ---------------------------------------------------------------------------
__global__ __launch_bounds__(256) void outproj_kernel(
    const unsigned short* __restrict__ A, const unsigned short* __restrict__ WoT,
    const float* __restrict__ bo, float* __restrict__ out)
{
    const int tid  = threadIdx.x;
    const int wave = tid >> 6;
    const int lane = tid & 63;
    const int c    = lane & 15;
    const int g    = lane >> 4;
    const int row0 = blockIdx.x * 64;
    const int n0   = wave * 64;

    f32x4 acc[4][4];
#pragma unroll
    for (int mt = 0; mt < 4; ++mt)
#pragma unroll
        for (int nt = 0; nt < 4; ++nt)
            acc[mt][nt] = (f32x4){0.f, 0.f, 0.f, 0.f};

    const unsigned short* Abase = A   + (size_t)(row0 + c) * 256 + 8 * g;
    const unsigned short* Bbase = WoT + (size_t)(n0   + c) * 256 + 8 * g;

#pragma unroll
    for (int ks = 0; ks < 8; ++ks) {
        bf16x8 a[4], b[4];
#pragma unroll
        for (int t = 0; t < 4; ++t) {
            a[t] = *(const bf16x8*)(Abase + (size_t)t * 16 * 256 + ks * 32);
            b[t] = *(const bf16x8*)(Bbase + (size_t)t * 16 * 256 + ks * 32);
        }
#pragma unroll
        for (int mt = 0; mt < 4; ++mt)
#pragma unroll
            for (int nt = 0; nt < 4; ++nt)
                acc[mt][nt] = __builtin_amdgcn_mfma_f32_16x16x32_bf16(
                    a[mt], b[nt], acc[mt][nt], 0, 0, 0);
    }

#pragma unroll
    for (int nt = 0; nt < 4; ++nt) {
        const int col  = n0 + nt * 16 + c;
        const float bias = bo[col];
#pragma unroll
        for (int mt = 0; mt < 4; ++mt) {
#pragma unroll
            for (int j = 0; j < 4; ++j) {
                const int row = row0 + mt * 16 + g * 4 + j;
                out[(size_t)row * 256 + col] = acc[mt][nt][j] + bias;
            }
        }
    }
}

// ---------------------------------------------------------------------------
extern "C" void kernel_launch(void* const* d_in, const int* in_sizes, int n_in,
                              void* d_out, int out_size, void* d_ws, size_t ws_size,
                              hipStream_t stream)
{
    const float* query  = (const float*)d_in[0];
    const float* value0 = (const float*)d_in[1];
    const float* value1 = (const float*)d_in[2];
    const float* value2 = (const float*)d_in[3];
    const float* refpts = (const float*)d_in[4];
    const float* Woff   = (const float*)d_in[5];
    const float* boff   = (const float*)d_in[6];
    const float* Wattn  = (const float*)d_in[7];
    const float* battn  = (const float*)d_in[8];
    const float* Wval   = (const float*)d_in[9];
    const float* bval   = (const float*)d_in[10];
    const float* Wout   = (const float*)d_in[11];
    const float* bout   = (const float*)d_in[12];
    float* out = (float*)d_out;

    // workspace layout:
    //   params : NQ*288 f32     = 46.08 MB
    //   v0/v1/v2 bf16           = 26.88 MB
    //   A_bf   : NQ*256 bf16    = 20.48 MB
    //   WoT    : 256*256 bf16   =  0.13 MB
    //   WTh/WTl: 288*256 bf16x2 =  0.29 MB     total ~93.9 MB
    float*          params = (float*)d_ws;
    unsigned short* v0   = (unsigned short*)(params + (size_t)NQ * 288);
    unsigned short* v1   = v0 + (size_t)BATCH * 10000 * 256;
    unsigned short* v2   = v1 + (size_t)BATCH * 2500  * 256;
    unsigned short* A_bf = v2 + (size_t)BATCH * 625   * 256;
    unsigned short* WoT  = A_bf + (size_t)NQ * 256;
    unsigned short* WTh  = WoT + (size_t)256 * 256;
    unsigned short* WTl  = WTh + (size_t)288 * 256;

    wprep_kernel<<<544, 256, 0, stream>>>(Woff, Wattn, Wout, WTh, WTl, WoT);

    vproj_kernel<<<dim3(207, BATCH), 256, 0, stream>>>(
        value0, value1, value2, Wval, bval, v0, v1, v2);

    qparam_kernel<<<NQ / 16, 64, 0, stream>>>(query, refpts, WTh, WTl,
                                              boff, battn, params);

    sample_kernel<<<NQ / 4, 256, 0, stream>>>(params, v0, v1, v2, A_bf);

    outproj_kernel<<<NQ / 64, 256, 0, stream>>>(A_bf, WoT, bout, out);
}

// Round 9
// 326.723 us; speedup vs baseline: 1.5149x; 1.1778x over previous
//
#include <hip/hip_runtime.h>
#include <math.h>

#define DMODEL 256
#define NHEAD 8
#define NLVL 3
#define NPTS 4
#define HDIM 32
#define QLEN 10000
#define BATCH 4
#define NQ (BATCH * QLEN)

typedef __attribute__((ext_vector_type(8))) short bf16x8;
typedef __attribute__((ext_vector_type(4))) float f32x4;

__device__ __forceinline__ float tanh_fast(float x)
{
    const float ax = fabsf(x);
    const float e  = __expf(-2.f * ax);
    const float t  = (1.f - e) / (1.f + e);
    return copysignf(t, x);
}

__device__ __forceinline__ unsigned short f2bf(float f)
{
    unsigned int u = __float_as_uint(f);
    u = (u + 0x7FFFu + ((u >> 16) & 1u)) >> 16;
    return (unsigned short)u;
}

__device__ __forceinline__ float bf2f(unsigned short s)
{
    return __uint_as_float(((unsigned int)s) << 16);
}

// ---------------------------------------------------------------------------
// K1: value projection -> bf16, all 3 levels in one grid, direct staging.
// ---------------------------------------------------------------------------
__global__ __launch_bounds__(256) void vproj_kernel(
    const float* __restrict__ feat0, const float* __restrict__ feat1,
    const float* __restrict__ feat2, const float* __restrict__ Wv,
    const float* __restrict__ bv,
    unsigned short* __restrict__ v0, unsigned short* __restrict__ v1,
    unsigned short* __restrict__ v2)
{
    __shared__ float As[16 * 64];    // [kk][pos]
    __shared__ float Ws[16 * 256];   // [kk][col]

    const int bx = blockIdx.x;
    const int b  = blockIdx.y;

    const float* feat;
    unsigned short* vout;
    int HW, pos0;
    if (bx < 157)      { feat = feat0; vout = v0; HW = 10000; pos0 = bx * 64; }
    else if (bx < 197) { feat = feat1; vout = v1; HW = 2500;  pos0 = (bx - 157) * 64; }
    else               { feat = feat2; vout = v2; HW = 625;   pos0 = (bx - 197) * 64; }

    const int tid  = threadIdx.x;
    const int tp   = tid >> 5;
    const int tc   = tid & 31;

    const int ap   = tid & 63;
    const int ak   = tid >> 6;
    const int wkk  = tid >> 6;
    const int wc4  = (tid & 63) * 4;

    float acc[8][8];
#pragma unroll
    for (int i = 0; i < 8; ++i)
#pragma unroll
        for (int j = 0; j < 8; ++j) acc[i][j] = 0.f;

    const float* fb = feat + (size_t)b * DMODEL * HW;
    const bool pvalid = (pos0 + ap) < HW;

    for (int k0 = 0; k0 < 256; k0 += 16) {
#pragma unroll
        for (int it = 0; it < 4; ++it) {
            const int kk = ak + it * 4;
            As[kk * 64 + ap] = pvalid ? fb[(size_t)(k0 + kk) * HW + pos0 + ap] : 0.f;
        }
#pragma unroll
        for (int j = 0; j < 4; ++j)
            *(float4*)&Ws[(wkk + 4 * j) * 256 + wc4] =
                *(const float4*)&Wv[(size_t)(k0 + wkk + 4 * j) * 256 + wc4];
        __syncthreads();

#pragma unroll
        for (int kk = 0; kk < 16; ++kk) {
            const float4 a0 = *(const float4*)&As[kk * 64 + tp * 8];
            const float4 a1 = *(const float4*)&As[kk * 64 + tp * 8 + 4];
            const float a[8] = {a0.x, a0.y, a0.z, a0.w, a1.x, a1.y, a1.z, a1.w};
            float w[8];
#pragma unroll
            for (int jj = 0; jj < 4; ++jj) {
                const float2 wv = *(const float2*)&Ws[kk * 256 + 2 * tc + 64 * jj];
                w[2 * jj]     = wv.x;
                w[2 * jj + 1] = wv.y;
            }
#pragma unroll
            for (int i = 0; i < 8; ++i)
#pragma unroll
                for (int j = 0; j < 8; ++j)
                    acc[i][j] = fmaf(a[i], w[j], acc[i][j]);
        }
        __syncthreads();
    }

    float bb[8];
#pragma unroll
    for (int jj = 0; jj < 4; ++jj) {
        const float2 bvv = *(const float2*)&bv[2 * tc + 64 * jj];
        bb[2 * jj]     = bvv.x;
        bb[2 * jj + 1] = bvv.y;
    }

    unsigned short* vb = vout + (size_t)b * HW * 256;
#pragma unroll
    for (int i = 0; i < 8; ++i) {
        const int p = pos0 + tp * 8 + i;
        if (p < HW) {
            unsigned int* vp = (unsigned int*)(vb + (size_t)p * 256);
#pragma unroll
            for (int jj = 0; jj < 4; ++jj) {
                const unsigned int lo = f2bf(acc[i][2 * jj]     + bb[2 * jj]);
                const unsigned int hi = f2bf(acc[i][2 * jj + 1] + bb[2 * jj + 1]);
                vp[tc + 32 * jj] = lo | (hi << 16);
            }
        }
    }
}

// ---------------------------------------------------------------------------
// K2a: weight prep (once).  blocks 0..287: split-transpose W_off|W_attn
// fp32 [k][288] -> WT_hi/WT_lo bf16 [n][k].  blocks 288..543: transpose
// W_out -> WoT bf16 [n][k].
// ---------------------------------------------------------------------------
__global__ __launch_bounds__(256) void wprep_kernel(
    const float* __restrict__ Woff, const float* __restrict__ Wattn,
    const float* __restrict__ Wout,
    unsigned short* __restrict__ WTh, unsigned short* __restrict__ WTl,
    unsigned short* __restrict__ WoT)
{
    const int k = threadIdx.x;
    const int n = blockIdx.x;
    if (n < 288) {
        const float w = (n < 192) ? Woff[(size_t)k * 192 + n]
                                  : Wattn[(size_t)k * 96 + (n - 192)];
        const unsigned short hi = f2bf(w);
        WTh[(size_t)n * 256 + k] = hi;
        WTl[(size_t)n * 256 + k] = f2bf(w - bf2f(hi));
    } else {
        const int nn = n - 288;
        WoT[(size_t)nn * 256 + k] = f2bf(Wout[(size_t)k * 256 + nn]);
    }
}

// ---------------------------------------------------------------------------
// K2b: query-side GEMM via bf16x3 MFMA with BLOCK-COOPERATIVE LDS B-staging.
// 4 waves/block, wave wt owns 16 rows (64 rows/block, 625 blocks).
// Per ks (32-k slice): stage B hi+lo [2][288][40] shorts into LDS (padded,
// <=2-way bank aliasing), then each wave: 2 query float4 loads (hi/lo split
// in regs) + 18 nt x {2 ds_read_b128 + 3 MFMA} into acc[18] (independent
// chains).  Epilogue: LG f32[4][16][292] OVERLAYS the dead B region after
// the k-loop; register softmax/tanh -> params (identical numerics).
// ---------------------------------------------------------------------------
__global__ __launch_bounds__(256) void qparam_kernel(
    const float* __restrict__ query, const float* __restrict__ ref,
    const unsigned short* __restrict__ WTh, const unsigned short* __restrict__ WTl,
    const float* __restrict__ boff, const float* __restrict__ battn,
    float* __restrict__ params)
{
    __shared__ __align__(16) char SH[74752];
    short* Bs = (short*)SH;                       // [2][288][40] = 46080 B
    float (*LG)[16][292] = (float (*)[16][292])SH; // 4 x 18688 B (after k-loop)

    const int tid  = threadIdx.x;
    const int wt   = tid >> 6;        // wave 0..3
    const int lane = tid & 63;
    const int c    = lane & 15;
    const int g    = lane >> 4;
    const int row0 = blockIdx.x * 64;

    f32x4 acc[18];
#pragma unroll
    for (int nt = 0; nt < 18; ++nt) acc[nt] = (f32x4){0.f, 0.f, 0.f, 0.f};

    const float* qrow = query + (size_t)(row0 + wt * 16 + c) * 256 + 8 * g;

    for (int ks = 0; ks < 8; ++ks) {
        // ---- stage B slice: 2304 x 16B chunks, 9 per thread ----
#pragma unroll
        for (int i = 0; i < 9; ++i) {
            const int ch  = tid + 256 * i;          // 0..2303
            const int hl  = ch >= 1152;
            const int rem = hl ? ch - 1152 : ch;
            const int col = rem >> 2;
            const int g16 = rem & 3;
            const unsigned short* src =
                (hl ? WTl : WTh) + (size_t)col * 256 + ks * 32 + g16 * 8;
            *(bf16x8*)(Bs + (hl * 288 + col) * 40 + g16 * 8) =
                *(const bf16x8*)src;
        }
        __syncthreads();

        // ---- A fragment: query fp32 -> hi/lo bf16 split ----
        const float4 q0 = *(const float4*)(qrow + ks * 32);
        const float4 q1 = *(const float4*)(qrow + ks * 32 + 4);
        const float av[8] = {q0.x, q0.y, q0.z, q0.w, q1.x, q1.y, q1.z, q1.w};
        bf16x8 a_hi, a_lo;
#pragma unroll
        for (int j = 0; j < 8; ++j) {
            const unsigned short hi = f2bf(av[j]);
            a_hi[j] = (short)hi;
            a_lo[j] = (short)f2bf(av[j] - bf2f(hi));
        }

        // ---- 18 independent acc chains ----
#pragma unroll
        for (int nt = 0; nt < 18; ++nt) {
            const int col = nt * 16 + c;
            const bf16x8 b_hi = *(const bf16x8*)(Bs + col * 40 + g * 8);
            const bf16x8 b_lo = *(const bf16x8*)(Bs + (288 + col) * 40 + g * 8);
            acc[nt] = __builtin_amdgcn_mfma_f32_16x16x32_bf16(a_hi, b_hi, acc[nt], 0, 0, 0);
            acc[nt] = __builtin_amdgcn_mfma_f32_16x16x32_bf16(a_lo, b_hi, acc[nt], 0, 0, 0);
            acc[nt] = __builtin_amdgcn_mfma_f32_16x16x32_bf16(a_hi, b_lo, acc[nt], 0, 0, 0);
        }
        __syncthreads();
    }

    // ---- logits -> LDS (B region is dead now) ----
#pragma unroll
    for (int nt = 0; nt < 18; ++nt)
#pragma unroll
        for (int j = 0; j < 4; ++j)
            LG[wt][4 * g + j][nt * 16 + c] = acc[nt][j];
    __syncthreads();

    // ---- epilogue: 2 (row,h) pairs per lane ----
#pragma unroll
    for (int i = 0; i < 2; ++i) {
        const int pair = lane + 64 * i;
        const int rl   = pair >> 3;
        const int h    = pair & 7;
        const int row  = row0 + wt * 16 + rl;

        float lg[36];
#pragma unroll
        for (int j = 0; j < 24; ++j) lg[j] = LG[wt][rl][h * 24 + j] + boff[h * 24 + j];
#pragma unroll
        for (int j = 0; j < 12; ++j) lg[24 + j] = LG[wt][rl][192 + h * 12 + j] + battn[h * 12 + j];

        float m = lg[24];
#pragma unroll
        for (int j = 1; j < 12; ++j) m = fmaxf(m, lg[24 + j]);
        float s = 0.f;
        float al[12];
#pragma unroll
        for (int j = 0; j < 12; ++j) { al[j] = __expf(lg[24 + j] - m); s += al[j]; }
        const float inv = 1.f / s;

        const float refx = ref[(size_t)row * 2 + 0];
        const float refy = ref[(size_t)row * 2 + 1];

        float outv[36];
#pragma unroll
        for (int l = 0; l < 3; ++l) {
            const float Wl = (l == 0) ? 100.f : (l == 1) ? 50.f : 25.f;
#pragma unroll
            for (int p = 0; p < 4; ++p) {
                const int j = l * 4 + p;
                const float ox = 0.5f * tanh_fast(lg[l * 8 + p * 2 + 0]);
                const float oy = 0.5f * tanh_fast(lg[l * 8 + p * 2 + 1]);
                outv[3 * j + 0] = (refx + ox) * Wl - 0.5f;
                outv[3 * j + 1] = (refy + oy) * Wl - 0.5f;
                outv[3 * j + 2] = al[j] * inv;
            }
        }

        float4* pp = (float4*)(params + (size_t)row * 288 + h * 36);
#pragma unroll
        for (int u = 0; u < 9; ++u)
            pp[u] = make_float4(outv[4 * u + 0], outv[4 * u + 1],
                                outv[4 * u + 2], outv[4 * u + 3]);
    }
}

// ---------------------------------------------------------------------------
// K3: sampler.  ONE WAVE = ONE QUERY.  Output bf16 (feeds MFMA outproj).
// ---------------------------------------------------------------------------
__global__ __launch_bounds__(256) void sample_kernel(
    const float* __restrict__ params,
    const unsigned short* __restrict__ v0,
    const unsigned short* __restrict__ v1,
    const unsigned short* __restrict__ v2,
    unsigned short* __restrict__ outp)
{
    const int tid  = threadIdx.x;
    const int lane = tid & 63;
    const int q    = blockIdx.x * 4 + (tid >> 6);
    const int h    = lane >> 3;
    const int qd   = lane & 7;
    const int b    = q / QLEN;

    const float4* pp = (const float4*)(params + (size_t)q * 288 + h * 36);
    float f[36];
#pragma unroll
    for (int i = 0; i < 9; ++i) {
        const float4 v = pp[i];
        f[4 * i + 0] = v.x; f[4 * i + 1] = v.y;
        f[4 * i + 2] = v.z; f[4 * i + 3] = v.w;
    }

    float o0 = 0.f, o1 = 0.f, o2 = 0.f, o3 = 0.f;

#pragma unroll
    for (int l = 0; l < 3; ++l) {
        const int Wl = (l == 0) ? 100 : (l == 1) ? 50 : 25;
        const int Hl = Wl;
        const unsigned short* vb =
            (l == 0) ? v0 + (size_t)b * 10000 * 256 :
            (l == 1) ? v1 + (size_t)b * 2500  * 256 :
                       v2 + (size_t)b * 625   * 256;

        int   cidx[16];
        float cwt[16];
#pragma unroll
        for (int p = 0; p < 4; ++p) {
            const int j = l * 4 + p;
            const float x  = f[3 * j + 0];
            const float y  = f[3 * j + 1];
            const float aw = f[3 * j + 2];
            const float xf = floorf(x), yf = floorf(y);
            const int   x0i = (int)xf, y0i = (int)yf;
            const float wx = x - xf, wy = y - yf;
#pragma unroll
            for (int cy = 0; cy < 2; ++cy) {
#pragma unroll
                for (int cx = 0; cx < 2; ++cx) {
                    const int xi = x0i + cx, yi = y0i + cy;
                    const bool valid =
                        (xi >= 0) & (xi < Wl) & (yi >= 0) & (yi < Hl);
                    const int xc = min(max(xi, 0), Wl - 1);
                    const int yc = min(max(yi, 0), Hl - 1);
                    const float w = aw * (cx ? wx : 1.f - wx)
                                       * (cy ? wy : 1.f - wy);
                    cidx[p * 4 + cy * 2 + cx] = yc * Wl + xc;
                    cwt [p * 4 + cy * 2 + cx] = valid ? w : 0.f;
                }
            }
        }
#pragma unroll
        for (int k = 0; k < 16; ++k) {
            const ushort4 u = *(const ushort4*)(vb +
                (size_t)cidx[k] * 256 + h * 32 + qd * 4);
            const float cw = cwt[k];
            o0 = fmaf(cw, bf2f(u.x), o0);
            o1 = fmaf(cw, bf2f(u.y), o1);
            o2 = fmaf(cw, bf2f(u.z), o2);
            o3 = fmaf(cw, bf2f(u.w), o3);
        }
    }

    unsigned int lo = (unsigned int)f2bf(o0) | ((unsigned int)f2bf(o1) << 16);
    unsigned int hi = (unsigned int)f2bf(o2) | ((unsigned int)f2bf(o3) << 16);
    *(uint2*)(outp + (size_t)q * 256 + lane * 4) = make_uint2(lo, hi);
}

// ---------------------------------------------------------------------------
// K4: output projection via bf16 MFMA (validated R7).
// ---------------------------------------------------------------------------
__global__ __launch_bounds__(256) void outproj_kernel(
    const unsigned short* __restrict__ A, const unsigned short* __restrict__ WoT,
    const float* __restrict__ bo, float* __restrict__ out)
{
    const int tid  = threadIdx.x;
    const int wave = tid >> 6;
    const int lane = tid & 63;
    const int c    = lane & 15;
    const int g    = lane >> 4;
    const int row0 = blockIdx.x * 64;
    const int n0   = wave * 64;

    f32x4 acc[4][4];
#pragma unroll
    for (int mt = 0; mt < 4; ++mt)
#pragma unroll
        for (int nt = 0; nt < 4; ++nt)
            acc[mt][nt] = (f32x4){0.f, 0.f, 0.f, 0.f};

    const unsigned short* Abase = A   + (size_t)(row0 + c) * 256 + 8 * g;
    const unsigned short* Bbase = WoT + (size_t)(n0   + c) * 256 + 8 * g;

#pragma unroll
    for (int ks = 0; ks < 8; ++ks) {
        bf16x8 a[4], b[4];
#pragma unroll
        for (int t = 0; t < 4; ++t) {
            a[t] = *(const bf16x8*)(Abase + (size_t)t * 16 * 256 + ks * 32);
            b[t] = *(const bf16x8*)(Bbase + (size_t)t * 16 * 256 + ks * 32);
        }
#pragma unroll
        for (int mt = 0; mt < 4; ++mt)
#pragma unroll
            for (int nt = 0; nt < 4; ++nt)
                acc[mt][nt] = __builtin_amdgcn_mfma_f32_16x16x32_bf16(
                    a[mt], b[nt], acc[mt][nt], 0, 0, 0);
    }

#pragma unroll
    for (int nt = 0; nt < 4; ++nt) {
        const int col  = n0 + nt * 16 + c;
        const float bias = bo[col];
#pragma unroll
        for (int mt = 0; mt < 4; ++mt) {
#pragma unroll
            for (int j = 0; j < 4; ++j) {
                const int row = row0 + mt * 16 + g * 4 + j;
                out[(size_t)row * 256 + col] = acc[mt][nt][j] + bias;
            }
        }
    }
}

// ---------------------------------------------------------------------------
extern "C" void kernel_launch(void* const* d_in, const int* in_sizes, int n_in,
                              void* d_out, int out_size, void* d_ws, size_t ws_size,
                              hipStream_t stream)
{
    const float* query  = (const float*)d_in[0];
    const float* value0 = (const float*)d_in[1];
    const float* value1 = (const float*)d_in[2];
    const float* value2 = (const float*)d_in[3];
    const float* refpts = (const float*)d_in[4];
    const float* Woff   = (const float*)d_in[5];
    const float* boff   = (const float*)d_in[6];
    const float* Wattn  = (const float*)d_in[7];
    const float* battn  = (const float*)d_in[8];
    const float* Wval   = (const float*)d_in[9];
    const float* bval   = (const float*)d_in[10];
    const float* Wout   = (const float*)d_in[11];
    const float* bout   = (const float*)d_in[12];
    float* out = (float*)d_out;

    // workspace layout:
    //   params : NQ*288 f32     = 46.08 MB
    //   v0/v1/v2 bf16           = 26.88 MB
    //   A_bf   : NQ*256 bf16    = 20.48 MB
    //   WoT    : 256*256 bf16   =  0.13 MB
    //   WTh/WTl: 288*256 bf16x2 =  0.29 MB     total ~93.9 MB
    float*          params = (float*)d_ws;
    unsigned short* v0   = (unsigned short*)(params + (size_t)NQ * 288);
    unsigned short* v1   = v0 + (size_t)BATCH * 10000 * 256;
    unsigned short* v2   = v1 + (size_t)BATCH * 2500  * 256;
    unsigned short* A_bf = v2 + (size_t)BATCH * 625   * 256;
    unsigned short* WoT  = A_bf + (size_t)NQ * 256;
    unsigned short* WTh  = WoT + (size_t)256 * 256;
    unsigned short* WTl  = WTh + (size_t)288 * 256;

    wprep_kernel<<<544, 256, 0, stream>>>(Woff, Wattn, Wout, WTh, WTl, WoT);

    vproj_kernel<<<dim3(207, BATCH), 256, 0, stream>>>(
        value0, value1, value2, Wval, bval, v0, v1, v2);

    qparam_kernel<<<NQ / 64, 256, 0, stream>>>(query, refpts, WTh, WTl,
                                               boff, battn, params);

    sample_kernel<<<NQ / 4, 256, 0, stream>>>(params, v0, v1, v2, A_bf);

    outproj_kernel<<<NQ / 64, 256, 0, stream>>>(A_bf, WoT, bout, out);
}

// Round 10
// 267.582 us; speedup vs baseline: 1.8497x; 1.2210x over previous
//
#include <hip/hip_runtime.h>
#include <math.h>

#define DMODEL 256
#define NHEAD 8
#define NLVL 3
#define NPTS 4
#define HDIM 32
#define QLEN 10000
#define BATCH 4
#define NQ (BATCH * QLEN)

typedef __attribute__((ext_vector_type(8))) short bf16x8;
typedef __attribute__((ext_vector_type(4))) float f32x4;

__device__ __forceinline__ float tanh_fast(float x)
{
    const float ax = fabsf(x);
    const float e  = __expf(-2.f * ax);
    const float t  = (1.f - e) / (1.f + e);
    return copysignf(t, x);
}

__device__ __forceinline__ unsigned short f2bf(float f)
{
    unsigned int u = __float_as_uint(f);
    u = (u + 0x7FFFu + ((u >> 16) & 1u)) >> 16;
    return (unsigned short)u;
}

__device__ __forceinline__ float bf2f(unsigned short s)
{
    return __uint_as_float(((unsigned int)s) << 16);
}

// ---------------------------------------------------------------------------
// K0: weight prep (once).
//   n in [0,288)  : split-transpose [W_off|W_attn] fp32 [k][288] -> WTh/WTl [n][k] bf16
//   n in [288,544): transpose W_out -> WoT [n][k] bf16
//   n in [544,800): split-transpose W_val -> WvTh/WvTl [n][k] bf16
// ---------------------------------------------------------------------------
__global__ __launch_bounds__(256) void wprep_kernel(
    const float* __restrict__ Woff, const float* __restrict__ Wattn,
    const float* __restrict__ Wout, const float* __restrict__ Wval,
    unsigned short* __restrict__ WTh, unsigned short* __restrict__ WTl,
    unsigned short* __restrict__ WoT,
    unsigned short* __restrict__ WvTh, unsigned short* __restrict__ WvTl)
{
    const int k = threadIdx.x;
    const int n = blockIdx.x;
    if (n < 288) {
        const float w = (n < 192) ? Woff[(size_t)k * 192 + n]
                                  : Wattn[(size_t)k * 96 + (n - 192)];
        const unsigned short hi = f2bf(w);
        WTh[(size_t)n * 256 + k] = hi;
        WTl[(size_t)n * 256 + k] = f2bf(w - bf2f(hi));
    } else if (n < 544) {
        const int nn = n - 288;
        WoT[(size_t)nn * 256 + k] = f2bf(Wout[(size_t)k * 256 + nn]);
    } else {
        const int nn = n - 544;
        const float w = Wval[(size_t)k * 256 + nn];
        const unsigned short hi = f2bf(w);
        WvTh[(size_t)nn * 256 + k] = hi;
        WvTl[(size_t)nn * 256 + k] = f2bf(w - bf2f(hi));
    }
}

// ---------------------------------------------------------------------------
// K1: value projection via bf16 MFMA (2-term: a_hi*b_hi + a_hi*b_lo).
// 64 pos x 256 cols per block; 4 waves, wave w owns cols [64w, 64w+64).
// feat tile staged transposed into LDS as bf16 subtiles [kc][64 pos][8k]
// (conflict-free b128 writes/reads); B-frags from WvTh/WvTl (L2-resident).
// ---------------------------------------------------------------------------
__global__ __launch_bounds__(256) void vproj_kernel(
    const float* __restrict__ feat0, const float* __restrict__ feat1,
    const float* __restrict__ feat2,
    const unsigned short* __restrict__ WvTh, const unsigned short* __restrict__ WvTl,
    const float* __restrict__ bv,
    unsigned short* __restrict__ v0, unsigned short* __restrict__ v1,
    unsigned short* __restrict__ v2)
{
    __shared__ short As[32 * 64 * 8];   // [kc][pos][8] = 32 KB

    const int bx = blockIdx.x;
    const int b  = blockIdx.y;

    const float* feat;
    unsigned short* vout;
    int HW, pos0;
    if (bx < 157)      { feat = feat0; vout = v0; HW = 10000; pos0 = bx * 64; }
    else if (bx < 197) { feat = feat1; vout = v1; HW = 2500;  pos0 = (bx - 157) * 64; }
    else               { feat = feat2; vout = v2; HW = 625;   pos0 = (bx - 197) * 64; }

    const int tid  = threadIdx.x;
    const int wv   = tid >> 6;
    const int lane = tid & 63;
    const int c    = lane & 15;
    const int g    = lane >> 4;

    // ---- stage feat[k][pos0..pos0+64) -> As bf16 (transposed subtiles) ----
    const int sp = tid & 63;                    // pos within tile
    const int kb = (tid >> 6) * 64;             // this wave's k range
    const bool pv = (pos0 + sp) < HW;
    const float* fcol = feat + (size_t)b * DMODEL * HW + pos0 + sp;

#pragma unroll
    for (int i = 0; i < 8; ++i) {               // 8 chunks of 8 k
        short h8[8];
#pragma unroll
        for (int j = 0; j < 8; ++j) {
            const int k = kb + i * 8 + j;
            const float f = pv ? fcol[(size_t)k * HW] : 0.f;
            h8[j] = (short)f2bf(f);
        }
        *(bf16x8*)&As[((size_t)(kb / 8 + i) * 64 + sp) * 8] = *(bf16x8*)h8;
    }
    __syncthreads();

    // ---- MFMA: acc[mt][nt], 16 independent chains ----
    f32x4 acc[4][4];
#pragma unroll
    for (int mt = 0; mt < 4; ++mt)
#pragma unroll
        for (int nt = 0; nt < 4; ++nt)
            acc[mt][nt] = (f32x4){0.f, 0.f, 0.f, 0.f};

#pragma unroll
    for (int ks = 0; ks < 8; ++ks) {
        bf16x8 a[4];
#pragma unroll
        for (int mt = 0; mt < 4; ++mt)
            a[mt] = *(const bf16x8*)&As[((size_t)(ks * 4 + g) * 64 + mt * 16 + c) * 8];
        bf16x8 bh[4], bl[4];
#pragma unroll
        for (int nt = 0; nt < 4; ++nt) {
            const size_t off = (size_t)(wv * 64 + nt * 16 + c) * 256 + ks * 32 + 8 * g;
            bh[nt] = *(const bf16x8*)(WvTh + off);
            bl[nt] = *(const bf16x8*)(WvTl + off);
        }
#pragma unroll
        for (int mt = 0; mt < 4; ++mt)
#pragma unroll
            for (int nt = 0; nt < 4; ++nt) {
                acc[mt][nt] = __builtin_amdgcn_mfma_f32_16x16x32_bf16(
                    a[mt], bh[nt], acc[mt][nt], 0, 0, 0);
                acc[mt][nt] = __builtin_amdgcn_mfma_f32_16x16x32_bf16(
                    a[mt], bl[nt], acc[mt][nt], 0, 0, 0);
            }
    }

    // ---- epilogue: +bias, round to bf16, store ----
    unsigned short* vb = vout + (size_t)b * HW * 256;
#pragma unroll
    for (int nt = 0; nt < 4; ++nt) {
        const int col  = wv * 64 + nt * 16 + c;
        const float bias = bv[col];
#pragma unroll
        for (int mt = 0; mt < 4; ++mt) {
#pragma unroll
            for (int j = 0; j < 4; ++j) {
                const int p = mt * 16 + g * 4 + j;
                if (pos0 + p < HW)
                    vb[(size_t)(pos0 + p) * 256 + col] = f2bf(acc[mt][nt][j] + bias);
            }
        }
    }
}

// ---------------------------------------------------------------------------
// K2: query-side GEMM via bf16x3 MFMA with block-cooperative LDS B-staging
// (validated R9).  4 waves/block, 64 rows/block.
// ---------------------------------------------------------------------------
__global__ __launch_bounds__(256) void qparam_kernel(
    const float* __restrict__ query, const float* __restrict__ ref,
    const unsigned short* __restrict__ WTh, const unsigned short* __restrict__ WTl,
    const float* __restrict__ boff, const float* __restrict__ battn,
    float* __restrict__ params)
{
    __shared__ __align__(16) char SH[74752];
    short* Bs = (short*)SH;                        // [2][288][40]
    float (*LG)[16][292] = (float (*)[16][292])SH; // overlays after k-loop

    const int tid  = threadIdx.x;
    const int wt   = tid >> 6;
    const int lane = tid & 63;
    const int c    = lane & 15;
    const int g    = lane >> 4;
    const int row0 = blockIdx.x * 64;

    f32x4 acc[18];
#pragma unroll
    for (int nt = 0; nt < 18; ++nt) acc[nt] = (f32x4){0.f, 0.f, 0.f, 0.f};

    const float* qrow = query + (size_t)(row0 + wt * 16 + c) * 256 + 8 * g;

    for (int ks = 0; ks < 8; ++ks) {
#pragma unroll
        for (int i = 0; i < 9; ++i) {
            const int ch  = tid + 256 * i;
            const int hl  = ch >= 1152;
            const int rem = hl ? ch - 1152 : ch;
            const int col = rem >> 2;
            const int g16 = rem & 3;
            const unsigned short* src =
                (hl ? WTl : WTh) + (size_t)col * 256 + ks * 32 + g16 * 8;
            *(bf16x8*)(Bs + (hl * 288 + col) * 40 + g16 * 8) =
                *(const bf16x8*)src;
        }
        __syncthreads();

        const float4 q0 = *(const float4*)(qrow + ks * 32);
        const float4 q1 = *(const float4*)(qrow + ks * 32 + 4);
        const float av[8] = {q0.x, q0.y, q0.z, q0.w, q1.x, q1.y, q1.z, q1.w};
        bf16x8 a_hi, a_lo;
#pragma unroll
        for (int j = 0; j < 8; ++j) {
            const unsigned short hi = f2bf(av[j]);
            a_hi[j] = (short)hi;
            a_lo[j] = (short)f2bf(av[j] - bf2f(hi));
        }

#pragma unroll
        for (int nt = 0; nt < 18; ++nt) {
            const int col = nt * 16 + c;
            const bf16x8 b_hi = *(const bf16x8*)(Bs + col * 40 + g * 8);
            const bf16x8 b_lo = *(const bf16x8*)(Bs + (288 + col) * 40 + g * 8);
            acc[nt] = __builtin_amdgcn_mfma_f32_16x16x32_bf16(a_hi, b_hi, acc[nt], 0, 0, 0);
            acc[nt] = __builtin_amdgcn_mfma_f32_16x16x32_bf16(a_lo, b_hi, acc[nt], 0, 0, 0);
            acc[nt] = __builtin_amdgcn_mfma_f32_16x16x32_bf16(a_hi, b_lo, acc[nt], 0, 0, 0);
        }
        __syncthreads();
    }

#pragma unroll
    for (int nt = 0; nt < 18; ++nt)
#pragma unroll
        for (int j = 0; j < 4; ++j)
            LG[wt][4 * g + j][nt * 16 + c] = acc[nt][j];
    __syncthreads();

#pragma unroll
    for (int i = 0; i < 2; ++i) {
        const int pair = lane + 64 * i;
        const int rl   = pair >> 3;
        const int h    = pair & 7;
        const int row  = row0 + wt * 16 + rl;

        float lg[36];
#pragma unroll
        for (int j = 0; j < 24; ++j) lg[j] = LG[wt][rl][h * 24 + j] + boff[h * 24 + j];
#pragma unroll
        for (int j = 0; j < 12; ++j) lg[24 + j] = LG[wt][rl][192 + h * 12 + j] + battn[h * 12 + j];

        float m = lg[24];
#pragma unroll
        for (int j = 1; j < 12; ++j) m = fmaxf(m, lg[24 + j]);
        float s = 0.f;
        float al[12];
#pragma unroll
        for (int j = 0; j < 12; ++j) { al[j] = __expf(lg[24 + j] - m); s += al[j]; }
        const float inv = 1.f / s;

        const float refx = ref[(size_t)row * 2 + 0];
        const float refy = ref[(size_t)row * 2 + 1];

        float outv[36];
#pragma unroll
        for (int l = 0; l < 3; ++l) {
            const float Wl = (l == 0) ? 100.f : (l == 1) ? 50.f : 25.f;
#pragma unroll
            for (int p = 0; p < 4; ++p) {
                const int j = l * 4 + p;
                const float ox = 0.5f * tanh_fast(lg[l * 8 + p * 2 + 0]);
                const float oy = 0.5f * tanh_fast(lg[l * 8 + p * 2 + 1]);
                outv[3 * j + 0] = (refx + ox) * Wl - 0.5f;
                outv[3 * j + 1] = (refy + oy) * Wl - 0.5f;
                outv[3 * j + 2] = al[j] * inv;
            }
        }

        float4* pp = (float4*)(params + (size_t)row * 288 + h * 36);
#pragma unroll
        for (int u = 0; u < 9; ++u)
            pp[u] = make_float4(outv[4 * u + 0], outv[4 * u + 1],
                                outv[4 * u + 2], outv[4 * u + 3]);
    }
}

// ---------------------------------------------------------------------------
// K3: sampler.  ONE WAVE = ONE QUERY.  Output bf16 (feeds MFMA outproj).
// ---------------------------------------------------------------------------
__global__ __launch_bounds__(256) void sample_kernel(
    const float* __restrict__ params,
    const unsigned short* __restrict__ v0,
    const unsigned short* __restrict__ v1,
    const unsigned short* __restrict__ v2,
    unsigned short* __restrict__ outp)
{
    const int tid  = threadIdx.x;
    const int lane = tid & 63;
    const int q    = blockIdx.x * 4 + (tid >> 6);
    const int h    = lane >> 3;
    const int qd   = lane & 7;
    const int b    = q / QLEN;

    const float4* pp = (const float4*)(params + (size_t)q * 288 + h * 36);
    float f[36];
#pragma unroll
    for (int i = 0; i < 9; ++i) {
        const float4 v = pp[i];
        f[4 * i + 0] = v.x; f[4 * i + 1] = v.y;
        f[4 * i + 2] = v.z; f[4 * i + 3] = v.w;
    }

    float o0 = 0.f, o1 = 0.f, o2 = 0.f, o3 = 0.f;

#pragma unroll
    for (int l = 0; l < 3; ++l) {
        const int Wl = (l == 0) ? 100 : (l == 1) ? 50 : 25;
        const int Hl = Wl;
        const unsigned short* vb =
            (l == 0) ? v0 + (size_t)b * 10000 * 256 :
            (l == 1) ? v1 + (size_t)b * 2500  * 256 :
                       v2 + (size_t)b * 625   * 256;

        int   cidx[16];
        float cwt[16];
#pragma unroll
        for (int p = 0; p < 4; ++p) {
            const int j = l * 4 + p;
            const float x  = f[3 * j + 0];
            const float y  = f[3 * j + 1];
            const float aw = f[3 * j + 2];
            const float xf = floorf(x), yf = floorf(y);
            const int   x0i = (int)xf, y0i = (int)yf;
            const float wx = x - xf, wy = y - yf;
#pragma unroll
            for (int cy = 0; cy < 2; ++cy) {
#pragma unroll
                for (int cx = 0; cx < 2; ++cx) {
                    const int xi = x0i + cx, yi = y0i + cy;
                    const bool valid =
                        (xi >= 0) & (xi < Wl) & (yi >= 0) & (yi < Hl);
                    const int xc = min(max(xi, 0), Wl - 1);
                    const int yc = min(max(yi, 0), Hl - 1);
                    const float w = aw * (cx ? wx : 1.f - wx)
                                       * (cy ? wy : 1.f - wy);
                    cidx[p * 4 + cy * 2 + cx] = yc * Wl + xc;
                    cwt [p * 4 + cy * 2 + cx] = valid ? w : 0.f;
                }
            }
        }
#pragma unroll
        for (int k = 0; k < 16; ++k) {
            const ushort4 u = *(const ushort4*)(vb +
                (size_t)cidx[k] * 256 + h * 32 + qd * 4);
            const float cw = cwt[k];
            o0 = fmaf(cw, bf2f(u.x), o0);
            o1 = fmaf(cw, bf2f(u.y), o1);
            o2 = fmaf(cw, bf2f(u.z), o2);
            o3 = fmaf(cw, bf2f(u.w), o3);
        }
    }

    unsigned int lo = (unsigned int)f2bf(o0) | ((unsigned int)f2bf(o1) << 16);
    unsigned int hi = (unsigned int)f2bf(o2) | ((unsigned int)f2bf(o3) << 16);
    *(uint2*)(outp + (size_t)q * 256 + lane * 4) = make_uint2(lo, hi);
}

// ---------------------------------------------------------------------------
// K4: output projection via bf16 MFMA (validated R7).
// ---------------------------------------------------------------------------
__global__ __launch_bounds__(256) void outproj_kernel(
    const unsigned short* __restrict__ A, const unsigned short* __restrict__ WoT,
    const float* __restrict__ bo, float* __restrict__ out)
{
    const int tid  = threadIdx.x;
    const int wave = tid >> 6;
    const int lane = tid & 63;
    const int c    = lane & 15;
    const int g    = lane >> 4;
    const int row0 = blockIdx.x * 64;
    const int n0   = wave * 64;

    f32x4 acc[4][4];
#pragma unroll
    for (int mt = 0; mt < 4; ++mt)
#pragma unroll
        for (int nt = 0; nt < 4; ++nt)
            acc[mt][nt] = (f32x4){0.f, 0.f, 0.f, 0.f};

    const unsigned short* Abase = A   + (size_t)(row0 + c) * 256 + 8 * g;
    const unsigned short* Bbase = WoT + (size_t)(n0   + c) * 256 + 8 * g;

#pragma unroll
    for (int ks = 0; ks < 8; ++ks) {
        bf16x8 a[4], bvec[4];
#pragma unroll
        for (int t = 0; t < 4; ++t) {
            a[t]    = *(const bf16x8*)(Abase + (size_t)t * 16 * 256 + ks * 32);
            bvec[t] = *(const bf16x8*)(Bbase + (size_t)t * 16 * 256 + ks * 32);
        }
#pragma unroll
        for (int mt = 0; mt < 4; ++mt)
#pragma unroll
            for (int nt = 0; nt < 4; ++nt)
                acc[mt][nt] = __builtin_amdgcn_mfma_f32_16x16x32_bf16(
                    a[mt], bvec[nt], acc[mt][nt], 0, 0, 0);
    }

#pragma unroll
    for (int nt = 0; nt < 4; ++nt) {
        const int col  = n0 + nt * 16 + c;
        const float bias = bo[col];
#pragma unroll
        for (int mt = 0; mt < 4; ++mt) {
#pragma unroll
            for (int j = 0; j < 4; ++j) {
                const int row = row0 + mt * 16 + g * 4 + j;
                out[(size_t)row * 256 + col] = acc[mt][nt][j] + bias;
            }
        }
    }
}

// ---------------------------------------------------------------------------
extern "C" void kernel_launch(void* const* d_in, const int* in_sizes, int n_in,
                              void* d_out, int out_size, void* d_ws, size_t ws_size,
                              hipStream_t stream)
{
    const float* query  = (const float*)d_in[0];
    const float* value0 = (const float*)d_in[1];
    const float* value1 = (const float*)d_in[2];
    const float* value2 = (const float*)d_in[3];
    const float* refpts = (const float*)d_in[4];
    const float* Woff   = (const float*)d_in[5];
    const float* boff   = (const float*)d_in[6];
    const float* Wattn  = (const float*)d_in[7];
    const float* battn  = (const float*)d_in[8];
    const float* Wval   = (const float*)d_in[9];
    const float* bval   = (const float*)d_in[10];
    const float* Wout   = (const float*)d_in[11];
    const float* bout   = (const float*)d_in[12];
    float* out = (float*)d_out;

    // workspace layout:
    //   params : NQ*288 f32       = 46.08 MB
    //   v0/v1/v2 bf16             = 26.88 MB
    //   A_bf   : NQ*256 bf16      = 20.48 MB
    //   WoT    : 256*256 bf16     =  0.13 MB
    //   WTh/WTl: 288*256 bf16 x2  =  0.29 MB
    //   WvTh/WvTl: 256*256 bf16x2 =  0.26 MB   total ~94.1 MB
    float*          params = (float*)d_ws;
    unsigned short* v0   = (unsigned short*)(params + (size_t)NQ * 288);
    unsigned short* v1   = v0 + (size_t)BATCH * 10000 * 256;
    unsigned short* v2   = v1 + (size_t)BATCH * 2500  * 256;
    unsigned short* A_bf = v2 + (size_t)BATCH * 625   * 256;
    unsigned short* WoT  = A_bf + (size_t)NQ * 256;
    unsigned short* WTh  = WoT + (size_t)256 * 256;
    unsigned short* WTl  = WTh + (size_t)288 * 256;
    unsigned short* WvTh = WTl + (size_t)288 * 256;
    unsigned short* WvTl = WvTh + (size_t)256 * 256;

    wprep_kernel<<<800, 256, 0, stream>>>(Woff, Wattn, Wout, Wval,
                                          WTh, WTl, WoT, WvTh, WvTl);

    vproj_kernel<<<dim3(207, BATCH), 256, 0, stream>>>(
        value0, value1, value2, WvTh, WvTl, bval, v0, v1, v2);

    qparam_kernel<<<NQ / 64, 256, 0, stream>>>(query, refpts, WTh, WTl,
                                               boff, battn, params);

    sample_kernel<<<NQ / 4, 256, 0, stream>>>(params, v0, v1, v2, A_bf);

    outproj_kernel<<<NQ / 64, 256, 0, stream>>>(A_bf, WoT, bout, out);
}

// Round 11
// 249.813 us; speedup vs baseline: 1.9813x; 1.0711x over previous
//
#include <hip/hip_runtime.h>
#include <math.h>

#define DMODEL 256
#define NHEAD 8
#define NLVL 3
#define NPTS 4
#define HDIM 32
#define QLEN 10000
#define BATCH 4
#define NQ (BATCH * QLEN)

typedef __attribute__((ext_vector_type(8))) short bf16x8;
typedef __attribute__((ext_vector_type(4))) float f32x4;

__device__ __forceinline__ float tanh_fast(float x)
{
    const float ax = fabsf(x);
    const float e  = __expf(-2.f * ax);
    const float t  = (1.f - e) / (1.f + e);
    return copysignf(t, x);
}

__device__ __forceinline__ unsigned short f2bf(float f)
{
    unsigned int u = __float_as_uint(f);
    u = (u + 0x7FFFu + ((u >> 16) & 1u)) >> 16;
    return (unsigned short)u;
}

__device__ __forceinline__ float bf2f(unsigned short s)
{
    return __uint_as_float(((unsigned int)s) << 16);
}

// ---------------------------------------------------------------------------
// K0: weight prep (once).
// ---------------------------------------------------------------------------
__global__ __launch_bounds__(256) void wprep_kernel(
    const float* __restrict__ Woff, const float* __restrict__ Wattn,
    const float* __restrict__ Wout, const float* __restrict__ Wval,
    unsigned short* __restrict__ WTh, unsigned short* __restrict__ WTl,
    unsigned short* __restrict__ WoT,
    unsigned short* __restrict__ WvTh, unsigned short* __restrict__ WvTl)
{
    const int k = threadIdx.x;
    const int n = blockIdx.x;
    if (n < 288) {
        const float w = (n < 192) ? Woff[(size_t)k * 192 + n]
                                  : Wattn[(size_t)k * 96 + (n - 192)];
        const unsigned short hi = f2bf(w);
        WTh[(size_t)n * 256 + k] = hi;
        WTl[(size_t)n * 256 + k] = f2bf(w - bf2f(hi));
    } else if (n < 544) {
        const int nn = n - 288;
        WoT[(size_t)nn * 256 + k] = f2bf(Wout[(size_t)k * 256 + nn]);
    } else {
        const int nn = n - 544;
        const float w = Wval[(size_t)k * 256 + nn];
        const unsigned short hi = f2bf(w);
        WvTh[(size_t)nn * 256 + k] = hi;
        WvTl[(size_t)nn * 256 + k] = f2bf(w - bf2f(hi));
    }
}

// ---------------------------------------------------------------------------
// K1: value projection via bf16 MFMA (validated R10).  Output layout is now
// HEAD-MAJOR: v[b][h][pos][32]  (only the epilogue store address changed).
// ---------------------------------------------------------------------------
__global__ __launch_bounds__(256) void vproj_kernel(
    const float* __restrict__ feat0, const float* __restrict__ feat1,
    const float* __restrict__ feat2,
    const unsigned short* __restrict__ WvTh, const unsigned short* __restrict__ WvTl,
    const float* __restrict__ bv,
    unsigned short* __restrict__ v0, unsigned short* __restrict__ v1,
    unsigned short* __restrict__ v2)
{
    __shared__ short As[32 * 64 * 8];   // [kc][pos][8] = 32 KB

    const int bx = blockIdx.x;
    const int b  = blockIdx.y;

    const float* feat;
    unsigned short* vout;
    int HW, pos0;
    if (bx < 157)      { feat = feat0; vout = v0; HW = 10000; pos0 = bx * 64; }
    else if (bx < 197) { feat = feat1; vout = v1; HW = 2500;  pos0 = (bx - 157) * 64; }
    else               { feat = feat2; vout = v2; HW = 625;   pos0 = (bx - 197) * 64; }

    const int tid  = threadIdx.x;
    const int wv   = tid >> 6;
    const int lane = tid & 63;
    const int c    = lane & 15;
    const int g    = lane >> 4;

    const int sp = tid & 63;
    const int kb = (tid >> 6) * 64;
    const bool pv = (pos0 + sp) < HW;
    const float* fcol = feat + (size_t)b * DMODEL * HW + pos0 + sp;

#pragma unroll
    for (int i = 0; i < 8; ++i) {
        short h8[8];
#pragma unroll
        for (int j = 0; j < 8; ++j) {
            const int k = kb + i * 8 + j;
            const float f = pv ? fcol[(size_t)k * HW] : 0.f;
            h8[j] = (short)f2bf(f);
        }
        *(bf16x8*)&As[((size_t)(kb / 8 + i) * 64 + sp) * 8] = *(bf16x8*)h8;
    }
    __syncthreads();

    f32x4 acc[4][4];
#pragma unroll
    for (int mt = 0; mt < 4; ++mt)
#pragma unroll
        for (int nt = 0; nt < 4; ++nt)
            acc[mt][nt] = (f32x4){0.f, 0.f, 0.f, 0.f};

#pragma unroll
    for (int ks = 0; ks < 8; ++ks) {
        bf16x8 a[4];
#pragma unroll
        for (int mt = 0; mt < 4; ++mt)
            a[mt] = *(const bf16x8*)&As[((size_t)(ks * 4 + g) * 64 + mt * 16 + c) * 8];
        bf16x8 bh[4], bl[4];
#pragma unroll
        for (int nt = 0; nt < 4; ++nt) {
            const size_t off = (size_t)(wv * 64 + nt * 16 + c) * 256 + ks * 32 + 8 * g;
            bh[nt] = *(const bf16x8*)(WvTh + off);
            bl[nt] = *(const bf16x8*)(WvTl + off);
        }
#pragma unroll
        for (int mt = 0; mt < 4; ++mt)
#pragma unroll
            for (int nt = 0; nt < 4; ++nt) {
                acc[mt][nt] = __builtin_amdgcn_mfma_f32_16x16x32_bf16(
                    a[mt], bh[nt], acc[mt][nt], 0, 0, 0);
                acc[mt][nt] = __builtin_amdgcn_mfma_f32_16x16x32_bf16(
                    a[mt], bl[nt], acc[mt][nt], 0, 0, 0);
            }
    }

    // ---- epilogue: +bias, bf16, store HEAD-MAJOR [b][h][pos][32] ----
    unsigned short* vb = vout + (size_t)b * NHEAD * HW * 32;
#pragma unroll
    for (int nt = 0; nt < 4; ++nt) {
        const int col  = wv * 64 + nt * 16 + c;
        const int hh   = col >> 5;
        const int cc   = col & 31;
        const float bias = bv[col];
#pragma unroll
        for (int mt = 0; mt < 4; ++mt) {
#pragma unroll
            for (int j = 0; j < 4; ++j) {
                const int p = mt * 16 + g * 4 + j;
                if (pos0 + p < HW)
                    vb[((size_t)hh * HW + pos0 + p) * 32 + cc] =
                        f2bf(acc[mt][nt][j] + bias);
            }
        }
    }
}

// ---------------------------------------------------------------------------
// K2: query-side GEMM via bf16x3 MFMA with block-cooperative LDS B-staging
// (validated R9).
// ---------------------------------------------------------------------------
__global__ __launch_bounds__(256) void qparam_kernel(
    const float* __restrict__ query, const float* __restrict__ ref,
    const unsigned short* __restrict__ WTh, const unsigned short* __restrict__ WTl,
    const float* __restrict__ boff, const float* __restrict__ battn,
    float* __restrict__ params)
{
    __shared__ __align__(16) char SH[74752];
    short* Bs = (short*)SH;                        // [2][288][40]
    float (*LG)[16][292] = (float (*)[16][292])SH; // overlays after k-loop

    const int tid  = threadIdx.x;
    const int wt   = tid >> 6;
    const int lane = tid & 63;
    const int c    = lane & 15;
    const int g    = lane >> 4;
    const int row0 = blockIdx.x * 64;

    f32x4 acc[18];
#pragma unroll
    for (int nt = 0; nt < 18; ++nt) acc[nt] = (f32x4){0.f, 0.f, 0.f, 0.f};

    const float* qrow = query + (size_t)(row0 + wt * 16 + c) * 256 + 8 * g;

    for (int ks = 0; ks < 8; ++ks) {
#pragma unroll
        for (int i = 0; i < 9; ++i) {
            const int ch  = tid + 256 * i;
            const int hl  = ch >= 1152;
            const int rem = hl ? ch - 1152 : ch;
            const int col = rem >> 2;
            const int g16 = rem & 3;
            const unsigned short* src =
                (hl ? WTl : WTh) + (size_t)col * 256 + ks * 32 + g16 * 8;
            *(bf16x8*)(Bs + (hl * 288 + col) * 40 + g16 * 8) =
                *(const bf16x8*)src;
        }
        __syncthreads();

        const float4 q0 = *(const float4*)(qrow + ks * 32);
        const float4 q1 = *(const float4*)(qrow + ks * 32 + 4);
        const float av[8] = {q0.x, q0.y, q0.z, q0.w, q1.x, q1.y, q1.z, q1.w};
        bf16x8 a_hi, a_lo;
#pragma unroll
        for (int j = 0; j < 8; ++j) {
            const unsigned short hi = f2bf(av[j]);
            a_hi[j] = (short)hi;
            a_lo[j] = (short)f2bf(av[j] - bf2f(hi));
        }

#pragma unroll
        for (int nt = 0; nt < 18; ++nt) {
            const int col = nt * 16 + c;
            const bf16x8 b_hi = *(const bf16x8*)(Bs + col * 40 + g * 8);
            const bf16x8 b_lo = *(const bf16x8*)(Bs + (288 + col) * 40 + g * 8);
            acc[nt] = __builtin_amdgcn_mfma_f32_16x16x32_bf16(a_hi, b_hi, acc[nt], 0, 0, 0);
            acc[nt] = __builtin_amdgcn_mfma_f32_16x16x32_bf16(a_lo, b_hi, acc[nt], 0, 0, 0);
            acc[nt] = __builtin_amdgcn_mfma_f32_16x16x32_bf16(a_hi, b_lo, acc[nt], 0, 0, 0);
        }
        __syncthreads();
    }

#pragma unroll
    for (int nt = 0; nt < 18; ++nt)
#pragma unroll
        for (int j = 0; j < 4; ++j)
            LG[wt][4 * g + j][nt * 16 + c] = acc[nt][j];
    __syncthreads();

#pragma unroll
    for (int i = 0; i < 2; ++i) {
        const int pair = lane + 64 * i;
        const int rl   = pair >> 3;
        const int h    = pair & 7;
        const int row  = row0 + wt * 16 + rl;

        float lg[36];
#pragma unroll
        for (int j = 0; j < 24; ++j) lg[j] = LG[wt][rl][h * 24 + j] + boff[h * 24 + j];
#pragma unroll
        for (int j = 0; j < 12; ++j) lg[24 + j] = LG[wt][rl][192 + h * 12 + j] + battn[h * 12 + j];

        float m = lg[24];
#pragma unroll
        for (int j = 1; j < 12; ++j) m = fmaxf(m, lg[24 + j]);
        float s = 0.f;
        float al[12];
#pragma unroll
        for (int j = 0; j < 12; ++j) { al[j] = __expf(lg[24 + j] - m); s += al[j]; }
        const float inv = 1.f / s;

        const float refx = ref[(size_t)row * 2 + 0];
        const float refy = ref[(size_t)row * 2 + 1];

        float outv[36];
#pragma unroll
        for (int l = 0; l < 3; ++l) {
            const float Wl = (l == 0) ? 100.f : (l == 1) ? 50.f : 25.f;
#pragma unroll
            for (int p = 0; p < 4; ++p) {
                const int j = l * 4 + p;
                const float ox = 0.5f * tanh_fast(lg[l * 8 + p * 2 + 0]);
                const float oy = 0.5f * tanh_fast(lg[l * 8 + p * 2 + 1]);
                outv[3 * j + 0] = (refx + ox) * Wl - 0.5f;
                outv[3 * j + 1] = (refy + oy) * Wl - 0.5f;
                outv[3 * j + 2] = al[j] * inv;
            }
        }

        float4* pp = (float4*)(params + (size_t)row * 288 + h * 36);
#pragma unroll
        for (int u = 0; u < 9; ++u)
            pp[u] = make_float4(outv[4 * u + 0], outv[4 * u + 1],
                                outv[4 * u + 2], outv[4 * u + 3]);
    }
}

// ---------------------------------------------------------------------------
// K3: sampler, HEAD-MAJOR.  Block = (32 queries, head h, batch b); wave =
// 8 queries x 1 head; lane = (qd 0..7, ch-oct 0..7).  Per-block working set
// is one head slice (<=640 KB, L2-resident).  Per corner load: 8 x 64B
// segments.  Output bf16 channel-major (unchanged layout for outproj).
// ---------------------------------------------------------------------------
__global__ __launch_bounds__(256) void sample_kernel(
    const float* __restrict__ params,
    const unsigned short* __restrict__ v0,
    const unsigned short* __restrict__ v1,
    const unsigned short* __restrict__ v2,
    unsigned short* __restrict__ outp)
{
    const int tid  = threadIdx.x;
    const int wv   = tid >> 6;
    const int lane = tid & 63;
    const int qd   = lane >> 3;      // query within wave
    const int co   = lane & 7;       // channel oct (4 ch)
    const int h    = blockIdx.y;
    const int b    = blockIdx.z;
    const int q    = blockIdx.x * 32 + wv * 8 + qd;
    if (q >= QLEN) return;           // wave-uniform exit (wv uniform)
    const int qq   = b * QLEN + q;

    const float4* pp = (const float4*)(params + (size_t)qq * 288 + h * 36);
    float f[36];
#pragma unroll
    for (int i = 0; i < 9; ++i) {
        const float4 v = pp[i];
        f[4 * i + 0] = v.x; f[4 * i + 1] = v.y;
        f[4 * i + 2] = v.z; f[4 * i + 3] = v.w;
    }

    float o0 = 0.f, o1 = 0.f, o2 = 0.f, o3 = 0.f;

#pragma unroll
    for (int l = 0; l < 3; ++l) {
        const int Wl = (l == 0) ? 100 : (l == 1) ? 50 : 25;
        const int Hl = Wl;
        const int HW = Wl * Hl;
        const unsigned short* vh =
            ((l == 0) ? v0 : (l == 1) ? v1 : v2) +
            ((size_t)(b * NHEAD + h) * HW) * 32;

        int   cidx[16];
        float cwt[16];
#pragma unroll
        for (int p = 0; p < 4; ++p) {
            const int j = l * 4 + p;
            const float x  = f[3 * j + 0];
            const float y  = f[3 * j + 1];
            const float aw = f[3 * j + 2];
            const float xf = floorf(x), yf = floorf(y);
            const int   x0i = (int)xf, y0i = (int)yf;
            const float wx = x - xf, wy = y - yf;
#pragma unroll
            for (int cy = 0; cy < 2; ++cy) {
#pragma unroll
                for (int cx = 0; cx < 2; ++cx) {
                    const int xi = x0i + cx, yi = y0i + cy;
                    const bool valid =
                        (xi >= 0) & (xi < Wl) & (yi >= 0) & (yi < Hl);
                    const int xc = min(max(xi, 0), Wl - 1);
                    const int yc = min(max(yi, 0), Hl - 1);
                    const float w = aw * (cx ? wx : 1.f - wx)
                                       * (cy ? wy : 1.f - wy);
                    cidx[p * 4 + cy * 2 + cx] = yc * Wl + xc;
                    cwt [p * 4 + cy * 2 + cx] = valid ? w : 0.f;
                }
            }
        }
#pragma unroll
        for (int k = 0; k < 16; ++k) {
            const ushort4 u = *(const ushort4*)(vh + (size_t)cidx[k] * 32 + co * 4);
            const float cw = cwt[k];
            o0 = fmaf(cw, bf2f(u.x), o0);
            o1 = fmaf(cw, bf2f(u.y), o1);
            o2 = fmaf(cw, bf2f(u.z), o2);
            o3 = fmaf(cw, bf2f(u.w), o3);
        }
    }

    unsigned int lo = (unsigned int)f2bf(o0) | ((unsigned int)f2bf(o1) << 16);
    unsigned int hi = (unsigned int)f2bf(o2) | ((unsigned int)f2bf(o3) << 16);
    *(uint2*)(outp + (size_t)qq * 256 + h * 32 + co * 4) = make_uint2(lo, hi);
}

// ---------------------------------------------------------------------------
// K4: output projection via bf16 MFMA (validated R7).
// ---------------------------------------------------------------------------
__global__ __launch_bounds__(256) void outproj_kernel(
    const unsigned short* __restrict__ A, const unsigned short* __restrict__ WoT,
    const float* __restrict__ bo, float* __restrict__ out)
{
    const int tid  = threadIdx.x;
    const int wave = tid >> 6;
    const int lane = tid & 63;
    const int c    = lane & 15;
    const int g    = lane >> 4;
    const int row0 = blockIdx.x * 64;
    const int n0   = wave * 64;

    f32x4 acc[4][4];
#pragma unroll
    for (int mt = 0; mt < 4; ++mt)
#pragma unroll
        for (int nt = 0; nt < 4; ++nt)
            acc[mt][nt] = (f32x4){0.f, 0.f, 0.f, 0.f};

    const unsigned short* Abase = A   + (size_t)(row0 + c) * 256 + 8 * g;
    const unsigned short* Bbase = WoT + (size_t)(n0   + c) * 256 + 8 * g;

#pragma unroll
    for (int ks = 0; ks < 8; ++ks) {
        bf16x8 a[4], bvec[4];
#pragma unroll
        for (int t = 0; t < 4; ++t) {
            a[t]    = *(const bf16x8*)(Abase + (size_t)t * 16 * 256 + ks * 32);
            bvec[t] = *(const bf16x8*)(Bbase + (size_t)t * 16 * 256 + ks * 32);
        }
#pragma unroll
        for (int mt = 0; mt < 4; ++mt)
#pragma unroll
            for (int nt = 0; nt < 4; ++nt)
                acc[mt][nt] = __builtin_amdgcn_mfma_f32_16x16x32_bf16(
                    a[mt], bvec[nt], acc[mt][nt], 0, 0, 0);
    }

#pragma unroll
    for (int nt = 0; nt < 4; ++nt) {
        const int col  = n0 + nt * 16 + c;
        const float bias = bo[col];
#pragma unroll
        for (int mt = 0; mt < 4; ++mt) {
#pragma unroll
            for (int j = 0; j < 4; ++j) {
                const int row = row0 + mt * 16 + g * 4 + j;
                out[(size_t)row * 256 + col] = acc[mt][nt][j] + bias;
            }
        }
    }
}

// ---------------------------------------------------------------------------
extern "C" void kernel_launch(void* const* d_in, const int* in_sizes, int n_in,
                              void* d_out, int out_size, void* d_ws, size_t ws_size,
                              hipStream_t stream)
{
    const float* query  = (const float*)d_in[0];
    const float* value0 = (const float*)d_in[1];
    const float* value1 = (const float*)d_in[2];
    const float* value2 = (const float*)d_in[3];
    const float* refpts = (const float*)d_in[4];
    const float* Woff   = (const float*)d_in[5];
    const float* boff   = (const float*)d_in[6];
    const float* Wattn  = (const float*)d_in[7];
    const float* battn  = (const float*)d_in[8];
    const float* Wval   = (const float*)d_in[9];
    const float* bval   = (const float*)d_in[10];
    const float* Wout   = (const float*)d_in[11];
    const float* bout   = (const float*)d_in[12];
    float* out = (float*)d_out;

    float*          params = (float*)d_ws;
    unsigned short* v0   = (unsigned short*)(params + (size_t)NQ * 288);
    unsigned short* v1   = v0 + (size_t)BATCH * 10000 * 256;
    unsigned short* v2   = v1 + (size_t)BATCH * 2500  * 256;
    unsigned short* A_bf = v2 + (size_t)BATCH * 625   * 256;
    unsigned short* WoT  = A_bf + (size_t)NQ * 256;
    unsigned short* WTh  = WoT + (size_t)256 * 256;
    unsigned short* WTl  = WTh + (size_t)288 * 256;
    unsigned short* WvTh = WTl + (size_t)288 * 256;
    unsigned short* WvTl = WvTh + (size_t)256 * 256;

    wprep_kernel<<<800, 256, 0, stream>>>(Woff, Wattn, Wout, Wval,
                                          WTh, WTl, WoT, WvTh, WvTl);

    vproj_kernel<<<dim3(207, BATCH), 256, 0, stream>>>(
        value0, value1, value2, WvTh, WvTl, bval, v0, v1, v2);

    qparam_kernel<<<NQ / 64, 256, 0, stream>>>(query, refpts, WTh, WTl,
                                               boff, battn, params);

    sample_kernel<<<dim3(313, NHEAD, BATCH), 256, 0, stream>>>(
        params, v0, v1, v2, A_bf);

    outproj_kernel<<<NQ / 64, 256, 0, stream>>>(A_bf, WoT, bout, out);
}

// Round 12
// 243.921 us; speedup vs baseline: 2.0291x; 1.0242x over previous
//
#include <hip/hip_runtime.h>
#include <math.h>

#define DMODEL 256
#define NHEAD 8
#define NLVL 3
#define NPTS 4
#define HDIM 32
#define QLEN 10000
#define BATCH 4
#define NQ (BATCH * QLEN)

typedef __attribute__((ext_vector_type(8))) short bf16x8;
typedef __attribute__((ext_vector_type(4))) float f32x4;

__device__ __forceinline__ float tanh_fast(float x)
{
    const float ax = fabsf(x);
    const float e  = __expf(-2.f * ax);
    const float t  = (1.f - e) / (1.f + e);
    return copysignf(t, x);
}

__device__ __forceinline__ unsigned short f2bf(float f)
{
    unsigned int u = __float_as_uint(f);
    u = (u + 0x7FFFu + ((u >> 16) & 1u)) >> 16;
    return (unsigned short)u;
}

__device__ __forceinline__ float bf2f(unsigned short s)
{
    return __uint_as_float(((unsigned int)s) << 16);
}

// ---------------------------------------------------------------------------
// K0: weight prep (once).
// ---------------------------------------------------------------------------
__global__ __launch_bounds__(256) void wprep_kernel(
    const float* __restrict__ Woff, const float* __restrict__ Wattn,
    const float* __restrict__ Wout, const float* __restrict__ Wval,
    unsigned short* __restrict__ WTh, unsigned short* __restrict__ WTl,
    unsigned short* __restrict__ WoT,
    unsigned short* __restrict__ WvTh, unsigned short* __restrict__ WvTl)
{
    const int k = threadIdx.x;
    const int n = blockIdx.x;
    if (n < 288) {
        const float w = (n < 192) ? Woff[(size_t)k * 192 + n]
                                  : Wattn[(size_t)k * 96 + (n - 192)];
        const unsigned short hi = f2bf(w);
        WTh[(size_t)n * 256 + k] = hi;
        WTl[(size_t)n * 256 + k] = f2bf(w - bf2f(hi));
    } else if (n < 544) {
        const int nn = n - 288;
        WoT[(size_t)nn * 256 + k] = f2bf(Wout[(size_t)k * 256 + nn]);
    } else {
        const int nn = n - 544;
        const float w = Wval[(size_t)k * 256 + nn];
        const unsigned short hi = f2bf(w);
        WvTh[(size_t)nn * 256 + k] = hi;
        WvTl[(size_t)nn * 256 + k] = f2bf(w - bf2f(hi));
    }
}

// ---------------------------------------------------------------------------
// K1: value projection via bf16 MFMA (validated R10/R11).  Output HEAD-MAJOR
// v[b][h][pos][32].
// ---------------------------------------------------------------------------
__global__ __launch_bounds__(256) void vproj_kernel(
    const float* __restrict__ feat0, const float* __restrict__ feat1,
    const float* __restrict__ feat2,
    const unsigned short* __restrict__ WvTh, const unsigned short* __restrict__ WvTl,
    const float* __restrict__ bv,
    unsigned short* __restrict__ v0, unsigned short* __restrict__ v1,
    unsigned short* __restrict__ v2)
{
    __shared__ short As[32 * 64 * 8];   // [kc][pos][8] = 32 KB

    const int bx = blockIdx.x;
    const int b  = blockIdx.y;

    const float* feat;
    unsigned short* vout;
    int HW, pos0;
    if (bx < 157)      { feat = feat0; vout = v0; HW = 10000; pos0 = bx * 64; }
    else if (bx < 197) { feat = feat1; vout = v1; HW = 2500;  pos0 = (bx - 157) * 64; }
    else               { feat = feat2; vout = v2; HW = 625;   pos0 = (bx - 197) * 64; }

    const int tid  = threadIdx.x;
    const int wv   = tid >> 6;
    const int lane = tid & 63;
    const int c    = lane & 15;
    const int g    = lane >> 4;

    const int sp = tid & 63;
    const int kb = (tid >> 6) * 64;
    const bool pv = (pos0 + sp) < HW;
    const float* fcol = feat + (size_t)b * DMODEL * HW + pos0 + sp;

#pragma unroll
    for (int i = 0; i < 8; ++i) {
        short h8[8];
#pragma unroll
        for (int j = 0; j < 8; ++j) {
            const int k = kb + i * 8 + j;
            const float f = pv ? fcol[(size_t)k * HW] : 0.f;
            h8[j] = (short)f2bf(f);
        }
        *(bf16x8*)&As[((size_t)(kb / 8 + i) * 64 + sp) * 8] = *(bf16x8*)h8;
    }
    __syncthreads();

    f32x4 acc[4][4];
#pragma unroll
    for (int mt = 0; mt < 4; ++mt)
#pragma unroll
        for (int nt = 0; nt < 4; ++nt)
            acc[mt][nt] = (f32x4){0.f, 0.f, 0.f, 0.f};

#pragma unroll
    for (int ks = 0; ks < 8; ++ks) {
        bf16x8 a[4];
#pragma unroll
        for (int mt = 0; mt < 4; ++mt)
            a[mt] = *(const bf16x8*)&As[((size_t)(ks * 4 + g) * 64 + mt * 16 + c) * 8];
        bf16x8 bh[4], bl[4];
#pragma unroll
        for (int nt = 0; nt < 4; ++nt) {
            const size_t off = (size_t)(wv * 64 + nt * 16 + c) * 256 + ks * 32 + 8 * g;
            bh[nt] = *(const bf16x8*)(WvTh + off);
            bl[nt] = *(const bf16x8*)(WvTl + off);
        }
#pragma unroll
        for (int mt = 0; mt < 4; ++mt)
#pragma unroll
            for (int nt = 0; nt < 4; ++nt) {
                acc[mt][nt] = __builtin_amdgcn_mfma_f32_16x16x32_bf16(
                    a[mt], bh[nt], acc[mt][nt], 0, 0, 0);
                acc[mt][nt] = __builtin_amdgcn_mfma_f32_16x16x32_bf16(
                    a[mt], bl[nt], acc[mt][nt], 0, 0, 0);
            }
    }

    unsigned short* vb = vout + (size_t)b * NHEAD * HW * 32;
#pragma unroll
    for (int nt = 0; nt < 4; ++nt) {
        const int col  = wv * 64 + nt * 16 + c;
        const int hh   = col >> 5;
        const int cc   = col & 31;
        const float bias = bv[col];
#pragma unroll
        for (int mt = 0; mt < 4; ++mt) {
#pragma unroll
            for (int j = 0; j < 4; ++j) {
                const int p = mt * 16 + g * 4 + j;
                if (pos0 + p < HW)
                    vb[((size_t)hh * HW + pos0 + p) * 32 + cc] =
                        f2bf(acc[mt][nt][j] + bias);
            }
        }
    }
}

// ---------------------------------------------------------------------------
// K2: query-side GEMM via bf16x3 MFMA, COL-SPLIT waves + conflict-free
// subtile LDS layout.
//   Block = 64 rows (4 row-tiles), 4 waves.  Wave wt owns cols nt = wt+4i
//   (5/5/4/4 of 18) and computes them for ALL 4 row-tiles: per ks it issues
//   only 2*|nt| ds_read_b128 (vs 36) -- 4x fewer LDS wave-instructions.
//   Bs[hl][nt][g][c][8] bf16: staging writes and frag reads are both the
//   contiguous-1KB conflict-free pattern; A-frags from global query (hi/lo
//   split in regs).  Epilogue: LG overlays Bs; wave wt finishes tile wt.
// ---------------------------------------------------------------------------
__global__ __launch_bounds__(256) void qparam_kernel(
    const float* __restrict__ query, const float* __restrict__ ref,
    const unsigned short* __restrict__ WTh, const unsigned short* __restrict__ WTl,
    const float* __restrict__ boff, const float* __restrict__ battn,
    float* __restrict__ params)
{
    __shared__ __align__(16) char SH[74752];
    short* Bs = (short*)SH;                        // [2][18][64][8] = 36864 B
    float (*LG)[16][292] = (float (*)[16][292])SH; // overlays after k-loop

    const int tid  = threadIdx.x;
    const int wt   = tid >> 6;
    const int lane = tid & 63;
    const int c    = lane & 15;
    const int g    = lane >> 4;
    const int row0 = blockIdx.x * 64;

    // staging offsets (WTl is contiguous after WTh: +288*256 elements)
    int srco[9], dsto[9];
#pragma unroll
    for (int i = 0; i < 9; ++i) {
        const int ch  = tid + 256 * i;            // 0..2303
        const int hl  = ch >= 1152;
        const int rem = hl ? ch - 1152 : ch;
        const int col = rem >> 2;
        const int gg  = rem & 3;
        srco[i] = hl * (288 * 256) + col * 256 + gg * 8;
        dsto[i] = (hl * 1152 + (col >> 4) * 64 + gg * 16 + (col & 15)) * 8;
    }

    // A-row base pointers (4 row-tiles)
    const float* qr[4];
#pragma unroll
    for (int t = 0; t < 4; ++t)
        qr[t] = query + (size_t)(row0 + t * 16 + c) * 256 + 8 * g;

    f32x4 acc[4][5];
#pragma unroll
    for (int t = 0; t < 4; ++t)
#pragma unroll
        for (int i = 0; i < 5; ++i) acc[t][i] = (f32x4){0.f, 0.f, 0.f, 0.f};

    for (int ks = 0; ks < 8; ++ks) {
        // ---- stage B slice (conflict-free contiguous writes) ----
#pragma unroll
        for (int i = 0; i < 9; ++i)
            *(bf16x8*)(Bs + dsto[i]) = *(const bf16x8*)(WTh + srco[i] + ks * 32);
        __syncthreads();

        // ---- A fragments for 4 row-tiles ----
        bf16x8 a_hi[4], a_lo[4];
#pragma unroll
        for (int t = 0; t < 4; ++t) {
            const float4 q0 = *(const float4*)(qr[t] + ks * 32);
            const float4 q1 = *(const float4*)(qr[t] + ks * 32 + 4);
            const float av[8] = {q0.x, q0.y, q0.z, q0.w, q1.x, q1.y, q1.z, q1.w};
#pragma unroll
            for (int j = 0; j < 8; ++j) {
                const unsigned short hi = f2bf(av[j]);
                a_hi[t][j] = (short)hi;
                a_lo[t][j] = (short)f2bf(av[j] - bf2f(hi));
            }
        }

        // ---- this wave's col tiles ----
#pragma unroll
        for (int i = 0; i < 5; ++i) {
            const int nt = wt + 4 * i;
            if (nt < 18) {
                const bf16x8 b_hi = *(const bf16x8*)(Bs + (nt * 64 + g * 16 + c) * 8);
                const bf16x8 b_lo = *(const bf16x8*)(Bs + (1152 + nt * 64 + g * 16 + c) * 8);
#pragma unroll
                for (int t = 0; t < 4; ++t) {
                    acc[t][i] = __builtin_amdgcn_mfma_f32_16x16x32_bf16(
                        a_hi[t], b_hi, acc[t][i], 0, 0, 0);
                    acc[t][i] = __builtin_amdgcn_mfma_f32_16x16x32_bf16(
                        a_lo[t], b_hi, acc[t][i], 0, 0, 0);
                    acc[t][i] = __builtin_amdgcn_mfma_f32_16x16x32_bf16(
                        a_hi[t], b_lo, acc[t][i], 0, 0, 0);
                }
            }
        }
        __syncthreads();
    }

    // ---- logits -> LG (B region dead) ----
#pragma unroll
    for (int i = 0; i < 5; ++i) {
        const int nt = wt + 4 * i;
        if (nt < 18) {
#pragma unroll
            for (int t = 0; t < 4; ++t)
#pragma unroll
                for (int j = 0; j < 4; ++j)
                    LG[t][4 * g + j][nt * 16 + c] = acc[t][i][j];
        }
    }
    __syncthreads();

    // ---- epilogue: wave wt finishes tile wt (2 (row,h) pairs per lane) ----
#pragma unroll
    for (int i = 0; i < 2; ++i) {
        const int pair = lane + 64 * i;
        const int rl   = pair >> 3;
        const int h    = pair & 7;
        const int row  = row0 + wt * 16 + rl;

        float lg[36];
#pragma unroll
        for (int j = 0; j < 24; ++j) lg[j] = LG[wt][rl][h * 24 + j] + boff[h * 24 + j];
#pragma unroll
        for (int j = 0; j < 12; ++j) lg[24 + j] = LG[wt][rl][192 + h * 12 + j] + battn[h * 12 + j];

        float m = lg[24];
#pragma unroll
        for (int j = 1; j < 12; ++j) m = fmaxf(m, lg[24 + j]);
        float s = 0.f;
        float al[12];
#pragma unroll
        for (int j = 0; j < 12; ++j) { al[j] = __expf(lg[24 + j] - m); s += al[j]; }
        const float inv = 1.f / s;

        const float refx = ref[(size_t)row * 2 + 0];
        const float refy = ref[(size_t)row * 2 + 1];

        float outv[36];
#pragma unroll
        for (int l = 0; l < 3; ++l) {
            const float Wl = (l == 0) ? 100.f : (l == 1) ? 50.f : 25.f;
#pragma unroll
            for (int p = 0; p < 4; ++p) {
                const int j = l * 4 + p;
                const float ox = 0.5f * tanh_fast(lg[l * 8 + p * 2 + 0]);
                const float oy = 0.5f * tanh_fast(lg[l * 8 + p * 2 + 1]);
                outv[3 * j + 0] = (refx + ox) * Wl - 0.5f;
                outv[3 * j + 1] = (refy + oy) * Wl - 0.5f;
                outv[3 * j + 2] = al[j] * inv;
            }
        }

        float4* pp = (float4*)(params + (size_t)row * 288 + h * 36);
#pragma unroll
        for (int u = 0; u < 9; ++u)
            pp[u] = make_float4(outv[4 * u + 0], outv[4 * u + 1],
                                outv[4 * u + 2], outv[4 * u + 3]);
    }
}

// ---------------------------------------------------------------------------
// K3: sampler, HEAD-MAJOR (validated R11).
// ---------------------------------------------------------------------------
__global__ __launch_bounds__(256) void sample_kernel(
    const float* __restrict__ params,
    const unsigned short* __restrict__ v0,
    const unsigned short* __restrict__ v1,
    const unsigned short* __restrict__ v2,
    unsigned short* __restrict__ outp)
{
    const int tid  = threadIdx.x;
    const int wv   = tid >> 6;
    const int lane = tid & 63;
    const int qd   = lane >> 3;
    const int co   = lane & 7;
    const int h    = blockIdx.y;
    const int b    = blockIdx.z;
    const int q    = blockIdx.x * 32 + wv * 8 + qd;
    if (q >= QLEN) return;
    const int qq   = b * QLEN + q;

    const float4* pp = (const float4*)(params + (size_t)qq * 288 + h * 36);
    float f[36];
#pragma unroll
    for (int i = 0; i < 9; ++i) {
        const float4 v = pp[i];
        f[4 * i + 0] = v.x; f[4 * i + 1] = v.y;
        f[4 * i + 2] = v.z; f[4 * i + 3] = v.w;
    }

    float o0 = 0.f, o1 = 0.f, o2 = 0.f, o3 = 0.f;

#pragma unroll
    for (int l = 0; l < 3; ++l) {
        const int Wl = (l == 0) ? 100 : (l == 1) ? 50 : 25;
        const int Hl = Wl;
        const int HW = Wl * Hl;
        const unsigned short* vh =
            ((l == 0) ? v0 : (l == 1) ? v1 : v2) +
            ((size_t)(b * NHEAD + h) * HW) * 32;

        int   cidx[16];
        float cwt[16];
#pragma unroll
        for (int p = 0; p < 4; ++p) {
            const int j = l * 4 + p;
            const float x  = f[3 * j + 0];
            const float y  = f[3 * j + 1];
            const float aw = f[3 * j + 2];
            const float xf = floorf(x), yf = floorf(y);
            const int   x0i = (int)xf, y0i = (int)yf;
            const float wx = x - xf, wy = y - yf;
#pragma unroll
            for (int cy = 0; cy < 2; ++cy) {
#pragma unroll
                for (int cx = 0; cx < 2; ++cx) {
                    const int xi = x0i + cx, yi = y0i + cy;
                    const bool valid =
                        (xi >= 0) & (xi < Wl) & (yi >= 0) & (yi < Hl);
                    const int xc = min(max(xi, 0), Wl - 1);
                    const int yc = min(max(yi, 0), Hl - 1);
                    const float w = aw * (cx ? wx : 1.f - wx)
                                       * (cy ? wy : 1.f - wy);
                    cidx[p * 4 + cy * 2 + cx] = yc * Wl + xc;
                    cwt [p * 4 + cy * 2 + cx] = valid ? w : 0.f;
                }
            }
        }
#pragma unroll
        for (int k = 0; k < 16; ++k) {
            const ushort4 u = *(const ushort4*)(vh + (size_t)cidx[k] * 32 + co * 4);
            const float cw = cwt[k];
            o0 = fmaf(cw, bf2f(u.x), o0);
            o1 = fmaf(cw, bf2f(u.y), o1);
            o2 = fmaf(cw, bf2f(u.z), o2);
            o3 = fmaf(cw, bf2f(u.w), o3);
        }
    }

    unsigned int lo = (unsigned int)f2bf(o0) | ((unsigned int)f2bf(o1) << 16);
    unsigned int hi = (unsigned int)f2bf(o2) | ((unsigned int)f2bf(o3) << 16);
    *(uint2*)(outp + (size_t)qq * 256 + h * 32 + co * 4) = make_uint2(lo, hi);
}

// ---------------------------------------------------------------------------
// K4: output projection via bf16 MFMA (validated R7).
// ---------------------------------------------------------------------------
__global__ __launch_bounds__(256) void outproj_kernel(
    const unsigned short* __restrict__ A, const unsigned short* __restrict__ WoT,
    const float* __restrict__ bo, float* __restrict__ out)
{
    const int tid  = threadIdx.x;
    const int wave = tid >> 6;
    const int lane = tid & 63;
    const int c    = lane & 15;
    const int g    = lane >> 4;
    const int row0 = blockIdx.x * 64;
    const int n0   = wave * 64;

    f32x4 acc[4][4];
#pragma unroll
    for (int mt = 0; mt < 4; ++mt)
#pragma unroll
        for (int nt = 0; nt < 4; ++nt)
            acc[mt][nt] = (f32x4){0.f, 0.f, 0.f, 0.f};

    const unsigned short* Abase = A   + (size_t)(row0 + c) * 256 + 8 * g;
    const unsigned short* Bbase = WoT + (size_t)(n0   + c) * 256 + 8 * g;

#pragma unroll
    for (int ks = 0; ks < 8; ++ks) {
        bf16x8 a[4], bvec[4];
#pragma unroll
        for (int t = 0; t < 4; ++t) {
            a[t]    = *(const bf16x8*)(Abase + (size_t)t * 16 * 256 + ks * 32);
            bvec[t] = *(const bf16x8*)(Bbase + (size_t)t * 16 * 256 + ks * 32);
        }
#pragma unroll
        for (int mt = 0; mt < 4; ++mt)
#pragma unroll
            for (int nt = 0; nt < 4; ++nt)
                acc[mt][nt] = __builtin_amdgcn_mfma_f32_16x16x32_bf16(
                    a[mt], bvec[nt], acc[mt][nt], 0, 0, 0);
    }

#pragma unroll
    for (int nt = 0; nt < 4; ++nt) {
        const int col  = n0 + nt * 16 + c;
        const float bias = bo[col];
#pragma unroll
        for (int mt = 0; mt < 4; ++mt) {
#pragma unroll
            for (int j = 0; j < 4; ++j) {
                const int row = row0 + mt * 16 + g * 4 + j;
                out[(size_t)row * 256 + col] = acc[mt][nt][j] + bias;
            }
        }
    }
}

// ---------------------------------------------------------------------------
extern "C" void kernel_launch(void* const* d_in, const int* in_sizes, int n_in,
                              void* d_out, int out_size, void* d_ws, size_t ws_size,
                              hipStream_t stream)
{
    const float* query  = (const float*)d_in[0];
    const float* value0 = (const float*)d_in[1];
    const float* value1 = (const float*)d_in[2];
    const float* value2 = (const float*)d_in[3];
    const float* refpts = (const float*)d_in[4];
    const float* Woff   = (const float*)d_in[5];
    const float* boff   = (const float*)d_in[6];
    const float* Wattn  = (const float*)d_in[7];
    const float* battn  = (const float*)d_in[8];
    const float* Wval   = (const float*)d_in[9];
    const float* bval   = (const float*)d_in[10];
    const float* Wout   = (const float*)d_in[11];
    const float* bout   = (const float*)d_in[12];
    float* out = (float*)d_out;

    float*          params = (float*)d_ws;
    unsigned short* v0   = (unsigned short*)(params + (size_t)NQ * 288);
    unsigned short* v1   = v0 + (size_t)BATCH * 10000 * 256;
    unsigned short* v2   = v1 + (size_t)BATCH * 2500  * 256;
    unsigned short* A_bf = v2 + (size_t)BATCH * 625   * 256;
    unsigned short* WoT  = A_bf + (size_t)NQ * 256;
    unsigned short* WTh  = WoT + (size_t)256 * 256;
    unsigned short* WTl  = WTh + (size_t)288 * 256;   // contiguous after WTh
    unsigned short* WvTh = WTl + (size_t)288 * 256;
    unsigned short* WvTl = WvTh + (size_t)256 * 256;

    wprep_kernel<<<800, 256, 0, stream>>>(Woff, Wattn, Wout, Wval,
                                          WTh, WTl, WoT, WvTh, WvTl);

    vproj_kernel<<<dim3(207, BATCH), 256, 0, stream>>>(
        value0, value1, value2, WvTh, WvTl, bval, v0, v1, v2);

    qparam_kernel<<<NQ / 64, 256, 0, stream>>>(query, refpts, WTh, WTl,
                                               boff, battn, params);

    sample_kernel<<<dim3(313, NHEAD, BATCH), 256, 0, stream>>>(
        params, v0, v1, v2, A_bf);

    outproj_kernel<<<NQ / 64, 256, 0, stream>>>(A_bf, WoT, bout, out);
}